// Round 14
// baseline (962.279 us; speedup 1.0000x reference)
//
#include <hip/hip_runtime.h>
#include <stdint.h>
#include <stddef.h>

typedef unsigned short u16;
typedef __attribute__((ext_vector_type(8))) short bf16x8;
typedef __attribute__((ext_vector_type(4))) float f32x4;

#define DEV __device__ __forceinline__

DEV float b2f(u16 u) { union { float f; uint32_t i; } v; v.i = ((uint32_t)u) << 16; return v.f; }
DEV u16 f2b(float f) {
  uint32_t x = __float_as_uint(f);
  x += 0x7fffu + ((x >> 16) & 1u);
  return (u16)(x >> 16);
}
DEV bf16x8 ld8f(const float* f) {
  float4 a = *(const float4*)f;
  float4 b = *(const float4*)(f + 4);
  bf16x8 r;
  ((u16*)&r)[0] = f2b(a.x); ((u16*)&r)[1] = f2b(a.y);
  ((u16*)&r)[2] = f2b(a.z); ((u16*)&r)[3] = f2b(a.w);
  ((u16*)&r)[4] = f2b(b.x); ((u16*)&r)[5] = f2b(b.y);
  ((u16*)&r)[6] = f2b(b.z); ((u16*)&r)[7] = f2b(b.w);
  return r;
}
DEV void gload16(const u16* g, u16* l) {
  __builtin_amdgcn_global_load_lds((const __attribute__((address_space(1))) void*)g,
                                   (__attribute__((address_space(3))) void*)l, 16, 0, 0);
}
DEV f32x4 mfma16(bf16x8 a, bf16x8 b, f32x4 c) {
  return __builtin_amdgcn_mfma_f32_16x16x32_bf16(a, b, c, 0, 0, 0);
}

// ---------- transpose f32 [K][N] -> bf16 [N][K], batched over z (tier0/1 path) ----------
__global__ __launch_bounds__(256) void transpose_w(const float* __restrict__ src,
                                                   u16* __restrict__ dst, int K, int N) {
  __shared__ u16 t[32][33];
  int tx = threadIdx.x, ty = threadIdx.y;
  int k0 = blockIdx.x * 32, n0 = blockIdx.y * 32;
  size_t base = (size_t)blockIdx.z * K * N;
#pragma unroll
  for (int i = 0; i < 4; i++) {
    int k = ty + 8 * i;
    t[k][tx] = f2b(src[base + (size_t)(k0 + k) * N + n0 + tx]);
  }
  __syncthreads();
#pragma unroll
  for (int i = 0; i < 4; i++) {
    int n = ty + 8 * i;
    dst[base + (size_t)(n0 + n) * K + k0 + tx] = t[tx][n];
  }
}

// ---------- merged QKV weight transpose: 3 tensors x 192 [1024][64] -> [N][K] bf16 ----------
__global__ __launch_bounds__(256) void transpose_qkvT(const float* __restrict__ s0,
                                                      const float* __restrict__ s1,
                                                      const float* __restrict__ s2,
                                                      u16* __restrict__ dst) {
  int z = blockIdx.z;
  const float* src = (z < 192) ? s0 : (z < 384) ? s1 : s2;
  int zi = (z < 192) ? z : (z < 384) ? z - 192 : z - 384;
  size_t sbase = (size_t)zi * 65536;
  size_t dbase = (size_t)z * 65536;
  __shared__ u16 t[32][33];
  int tx = threadIdx.x, ty = threadIdx.y;
  int k0 = blockIdx.x * 32, n0 = blockIdx.y * 32;
#pragma unroll
  for (int i = 0; i < 4; i++) {
    int k = ty + 8 * i;
    t[k][tx] = f2b(src[sbase + (size_t)(k0 + k) * 64 + n0 + tx]);
  }
  __syncthreads();
#pragma unroll
  for (int i = 0; i < 4; i++) {
    int n = ty + 8 * i;
    dst[dbase + (size_t)(n0 + n) * 1024 + k0 + tx] = t[tx][n];
  }
}

// ---------- merged FC weight transpose: 4 tensors x 4 layers [1024][1024] ----------
__global__ __launch_bounds__(256) void transpose_fcT(const float* __restrict__ s0,
                                                     const float* __restrict__ s1,
                                                     const float* __restrict__ s2,
                                                     const float* __restrict__ s3,
                                                     u16* __restrict__ dst) {
  int z = blockIdx.z;
  const float* src = (z < 4) ? s0 : (z < 8) ? s1 : (z < 12) ? s2 : s3;
  size_t sbase = (size_t)(z & 3) * 1048576;
  size_t dbase = (size_t)z * 1048576;
  __shared__ u16 t[32][33];
  int tx = threadIdx.x, ty = threadIdx.y;
  int k0 = blockIdx.x * 32, n0 = blockIdx.y * 32;
#pragma unroll
  for (int i = 0; i < 4; i++) {
    int k = ty + 8 * i;
    t[k][tx] = f2b(src[sbase + (size_t)(k0 + k) * 1024 + n0 + tx]);
  }
  __syncthreads();
#pragma unroll
  for (int i = 0; i < 4; i++) {
    int n = ty + 8 * i;
    dst[dbase + (size_t)(n0 + n) * 1024 + k0 + tx] = t[tx][n];
  }
}

// ---------- embedding gather + sinusoidal positional encoding ----------
__global__ __launch_bounds__(256) void embed_k(const int* __restrict__ tok, const float* __restrict__ emb,
                                               float* __restrict__ o32, u16* __restrict__ ob, int shift) {
  int row = blockIdx.x;
  int b = row >> 9, l = row & 511;
  int tk = tok[(size_t)(l + shift) * 2 + b];
  const float* e = emb + (size_t)tk * 1024;
  const float c0 = -9.210340371976184f / 1024.f;
#pragma unroll
  for (int i = 0; i < 4; i++) {
    int d = threadIdx.x + i * 256;
    int j2 = d & ~1;
    float ang = (float)l * expf(c0 * (float)j2);
    float pe = (d & 1) ? cosf(ang) : sinf(ang);
    float rv = e[d] + pe;
    o32[(size_t)row * 1024 + d] = rv;
    ob[(size_t)row * 1024 + d] = f2b(rv);
  }
}

// ---------- LayerNorm (input d already includes residual), fp32 in, fp32+bf16 out ----------
__global__ __launch_bounds__(256) void ln_k(const float* d,
                                            const float* __restrict__ g, const float* __restrict__ bb,
                                            float* o32, u16* __restrict__ ob) {
  int row = blockIdx.x;
  int tid = threadIdx.x;
  const float4 dv = ((const float4*)(d + (size_t)row * 1024))[tid];
  float v[4] = {dv.x, dv.y, dv.z, dv.w};
  float s = 0.f, s2 = 0.f;
#pragma unroll
  for (int i = 0; i < 4; i++) { s += v[i]; s2 += v[i] * v[i]; }
#pragma unroll
  for (int off = 1; off < 64; off <<= 1) {
    s += __shfl_xor(s, off);
    s2 += __shfl_xor(s2, off);
  }
  __shared__ float red[8];
  int wid = tid >> 6;
  if ((tid & 63) == 0) { red[wid * 2] = s; red[wid * 2 + 1] = s2; }
  __syncthreads();
  s = red[0] + red[2] + red[4] + red[6];
  s2 = red[1] + red[3] + red[5] + red[7];
  float mu = s * (1.f / 1024.f);
  float var = s2 * (1.f / 1024.f) - mu * mu;
  float inv = rsqrtf(var + 1e-5f);
  const float4 gv = ((const float4*)g)[tid];
  const float4 bv = ((const float4*)bb)[tid];
  float4 ov;
  ov.x = (v[0] - mu) * inv * gv.x + bv.x;
  ov.y = (v[1] - mu) * inv * gv.y + bv.y;
  ov.z = (v[2] - mu) * inv * gv.z + bv.z;
  ov.w = (v[3] - mu) * inv * gv.w + bv.w;
  ((float4*)(o32 + (size_t)row * 1024))[tid] = ov;
  uint2 p;
  p.x = (uint32_t)f2b(ov.x) | ((uint32_t)f2b(ov.y) << 16);
  p.y = (uint32_t)f2b(ov.z) | ((uint32_t)f2b(ov.w) << 16);
  ((uint2*)(ob + (size_t)row * 1024))[tid] = p;
}

// ---------- FFN GEMM: 64x64 tile, BK=64, depth-2 counted-vmcnt pipeline ----------
template <bool RELU>
__global__ __launch_bounds__(256) void gemm_fc(const u16* __restrict__ A, const u16* __restrict__ BT,
                                               const float* __restrict__ bias,
                                               const float* __restrict__ resid, void* __restrict__ out,
                                               int N, int K) {
  __shared__ __align__(16) u16 lA[2][2][64 * 32];
  __shared__ __align__(16) u16 lB[2][2][64 * 32];
  int bx = blockIdx.x, by = blockIdx.y;
  int tid = threadIdx.x, lane = tid & 63, wid = tid >> 6;
  int l15 = lane & 15, lg = lane >> 4;
  int bm = by * 64, bn = bx * 64;
  int wr = (wid >> 1) * 32, wc = (wid & 1) * 32;
  f32x4 acc[2][2] = {};
  int r_s = tid >> 2, c_s = tid & 3;
  auto stage = [&](int pp, int kt) {
#pragma unroll
    for (int s = 0; s < 2; s++) {
      gload16(A + (size_t)(bm + r_s) * K + kt + s * 32 + c_s * 8, &lA[pp][s][(size_t)(wid * 64) * 8]);
      gload16(BT + (size_t)(bn + r_s) * K + kt + s * 32 + c_s * 8, &lB[pp][s][(size_t)(wid * 64) * 8]);
    }
  };
  int nt = K >> 6;
  stage(0, 0);
  int pp = 0;
  for (int t = 0; t < nt; t++) {
    if (t + 1 < nt) {
      stage(pp ^ 1, (t + 1) * 64);
      asm volatile("s_waitcnt vmcnt(4)" ::: "memory");
    } else {
      asm volatile("s_waitcnt vmcnt(0)" ::: "memory");
    }
    __builtin_amdgcn_s_barrier();
#pragma unroll
    for (int s = 0; s < 2; s++) {
      bf16x8 af[2], bf_[2];
#pragma unroll
      for (int m = 0; m < 2; m++) af[m] = *(const bf16x8*)&lA[pp][s][(wr + m * 16 + l15) * 32 + lg * 8];
#pragma unroll
      for (int n = 0; n < 2; n++) bf_[n] = *(const bf16x8*)&lB[pp][s][(wc + n * 16 + l15) * 32 + lg * 8];
#pragma unroll
      for (int m = 0; m < 2; m++)
#pragma unroll
        for (int n = 0; n < 2; n++) acc[m][n] = mfma16(af[m], bf_[n], acc[m][n]);
    }
    __builtin_amdgcn_s_barrier();
    pp ^= 1;
  }
#pragma unroll
  for (int n = 0; n < 2; n++) {
    int col = bn + wc + n * 16 + l15;
    float bv = bias[col];
#pragma unroll
    for (int m = 0; m < 2; m++) {
#pragma unroll
      for (int r = 0; r < 4; r++) {
        int row = bm + wr + m * 16 + lg * 4 + r;
        float v = acc[m][n][r] + bv;
        if (RELU) ((u16*)out)[(size_t)row * N + col] = f2b(fmaxf(v, 0.f));
        else ((float*)out)[(size_t)row * N + col] = v + resid[(size_t)row * N + col];
      }
    }
  }
}

// ---------- fused QKV projection, 64x64 tiles, BK=64, depth-2 pipeline ----------
__global__ __launch_bounds__(256) void gemm_qkv3(const u16* __restrict__ Aq, const u16* __restrict__ Akv,
                                                 const u16* __restrict__ WT, const float* __restrict__ bias,
                                                 u16* __restrict__ Qo, u16* __restrict__ Ko,
                                                 u16* __restrict__ Vto) {
  __shared__ __align__(16) u16 lA[2][2][64 * 32];
  __shared__ __align__(16) u16 lB[2][2][64 * 32];
  int bx = blockIdx.x, by = blockIdx.y;
  int t_ = bx >> 4;
  const u16* A = (t_ == 0) ? Aq : Akv;
  int tid = threadIdx.x, lane = tid & 63, wid = tid >> 6;
  int l15 = lane & 15, lg = lane >> 4;
  int bm = by * 64, bn = bx * 64;
  int wr = (wid >> 1) * 32, wc = (wid & 1) * 32;
  f32x4 acc[2][2] = {};
  int r_s = tid >> 2, c_s = tid & 3;
  auto stage = [&](int pp, int kt) {
#pragma unroll
    for (int s = 0; s < 2; s++) {
      gload16(A + (size_t)(bm + r_s) * 1024 + kt + s * 32 + c_s * 8, &lA[pp][s][(size_t)(wid * 64) * 8]);
      gload16(WT + (size_t)(bn + r_s) * 1024 + kt + s * 32 + c_s * 8, &lB[pp][s][(size_t)(wid * 64) * 8]);
    }
  };
  stage(0, 0);
  int pp = 0;
  for (int t = 0; t < 16; t++) {
    if (t + 1 < 16) {
      stage(pp ^ 1, (t + 1) * 64);
      asm volatile("s_waitcnt vmcnt(4)" ::: "memory");
    } else {
      asm volatile("s_waitcnt vmcnt(0)" ::: "memory");
    }
    __builtin_amdgcn_s_barrier();
#pragma unroll
    for (int s = 0; s < 2; s++) {
      bf16x8 af[2], bf_[2];
#pragma unroll
      for (int m = 0; m < 2; m++) af[m] = *(const bf16x8*)&lA[pp][s][(wr + m * 16 + l15) * 32 + lg * 8];
#pragma unroll
      for (int n = 0; n < 2; n++) bf_[n] = *(const bf16x8*)&lB[pp][s][(wc + n * 16 + l15) * 32 + lg * 8];
#pragma unroll
      for (int m = 0; m < 2; m++)
#pragma unroll
        for (int n = 0; n < 2; n++) acc[m][n] = mfma16(af[m], bf_[n], acc[m][n]);
    }
    __builtin_amdgcn_s_barrier();
    pp ^= 1;
  }
#pragma unroll
  for (int n = 0; n < 2; n++) {
    int col = bn + wc + n * 16 + l15;
    int h = (col >> 6) & 15, e = col & 63;
    float bv = bias[col];
#pragma unroll
    for (int m = 0; m < 2; m++) {
#pragma unroll
      for (int r = 0; r < 4; r++) {
        int row = bm + wr + m * 16 + lg * 4 + r;
        int b = row >> 9, l = row & 511;
        u16 vbv = f2b(acc[m][n][r] + bv);
        size_t bhead = (size_t)b * 16 + h;
        if (t_ == 0) Qo[(bhead * 512 + l) * 64 + e] = vbv;
        else if (t_ == 1) Ko[(bhead * 512 + l) * 64 + e] = vbv;
        else Vto[(bhead * 64 + e) * 512 + l] = vbv;
      }
    }
  }
}

// ---------- final projection: 256x256 tile, 8 waves, BK=32, depth-2 counted-vmcnt ----------
// Same proven schedule as gemm_fc (stage -> vmcnt(4) -> barrier -> compute -> barrier),
// scaled to 2x arithmetic intensity (32 MFMA : 12 ds_read per wave-iteration).
// Grid 512 (1D); bijective panel-per-XCD swizzle: p=(b&7)+8*(b>>5) [guard >=125], row=(b>>3)&3.
__global__ __launch_bounds__(512) void gemm_f256(const u16* __restrict__ A, const u16* __restrict__ BT,
                                                 const float* __restrict__ bias, float* __restrict__ out,
                                                 int N, int K) {
  __shared__ __align__(16) u16 lA[2][256 * 32];
  __shared__ __align__(16) u16 lB[2][256 * 32];
  int b = blockIdx.x;
  int p = (b & 7) + 8 * (b >> 5);
  if (p >= N / 256) return;
  int brow = (b >> 3) & 3;
  int tid = threadIdx.x, lane = tid & 63, wid = tid >> 6;
  int l15 = lane & 15, lg = lane >> 4;
  int bm = brow * 256, bn = p * 256;
  int wrow = (wid >> 2) * 128, wcol = (wid & 3) * 64;  // 8 waves = 2M x 4N; per wave 128x64
  f32x4 acc[8][4] = {};
  int r_s = tid >> 2, c_s = tid & 3;  // r_s 0..127
  auto stage = [&](int pp, int kt) {
#pragma unroll
    for (int i = 0; i < 2; i++) {
      gload16(A + (size_t)(bm + i * 128 + r_s) * K + kt + c_s * 8, &lA[pp][(size_t)(i * 512 + tid) * 8]);
      gload16(BT + (size_t)(bn + i * 128 + r_s) * K + kt + c_s * 8, &lB[pp][(size_t)(i * 512 + tid) * 8]);
    }
  };
  int nt = K >> 5;  // 32
  stage(0, 0);
  int pp = 0;
  for (int t = 0; t < nt; t++) {
    if (t + 1 < nt) {
      stage(pp ^ 1, (t + 1) * 32);
      asm volatile("s_waitcnt vmcnt(4)" ::: "memory");
    } else {
      asm volatile("s_waitcnt vmcnt(0)" ::: "memory");
    }
    __builtin_amdgcn_s_barrier();
    bf16x8 af[8], bf_[4];
#pragma unroll
    for (int m = 0; m < 8; m++) af[m] = *(const bf16x8*)&lA[pp][(wrow + m * 16 + l15) * 32 + lg * 8];
#pragma unroll
    for (int n = 0; n < 4; n++) bf_[n] = *(const bf16x8*)&lB[pp][(wcol + n * 16 + l15) * 32 + lg * 8];
#pragma unroll
    for (int m = 0; m < 8; m++)
#pragma unroll
      for (int n = 0; n < 4; n++) acc[m][n] = mfma16(af[m], bf_[n], acc[m][n]);
    __builtin_amdgcn_s_barrier();
    pp ^= 1;
  }
#pragma unroll
  for (int n = 0; n < 4; n++) {
    int col = bn + wcol + n * 16 + l15;
    float bv = bias[col];
#pragma unroll
    for (int m = 0; m < 8; m++) {
#pragma unroll
      for (int r = 0; r < 4; r++) {
        int row = bm + wrow + m * 16 + lg * 4 + r;
        out[(size_t)row * N + col] = acc[m][n][r] + bv;
      }
    }
  }
}

// ---------- fallback final projection (tier0): A bf16; B f32 [K][N]; out f32 ----------
__global__ __launch_bounds__(256) void gemm_bn(const u16* __restrict__ A, const float* __restrict__ B,
                                               const float* __restrict__ bias, float* __restrict__ out,
                                               int N, int K) {
  __shared__ __align__(16) u16 lA[128 * 32];
  __shared__ __align__(16) u16 lBn[32 * 128];
  int b = blockIdx.x;
  int p = (b & 7) + 8 * (b >> 6);
  if (p >= N / 128) return;
  int by = (b >> 3) & 7;
  int tid = threadIdx.x, lane = tid & 63;
  int wid = tid >> 6;
  int l15 = lane & 15, lg = lane >> 4;
  int bm = by * 128, bn = p * 128;
  int wr = (wid >> 1) * 64, wc = (wid & 1) * 64;
  f32x4 acc[4][4] = {};
  int r_s = tid >> 2, c_s = tid & 3;
  int br = tid >> 4, bc = tid & 15;
  for (int kt = 0; kt < K; kt += 32) {
    bf16x8 va[2], vb[2];
#pragma unroll
    for (int it = 0; it < 2; it++) {
      va[it] = *(const bf16x8*)&A[(size_t)(bm + it * 64 + r_s) * K + kt + c_s * 8];
      vb[it] = ld8f(B + (size_t)(kt + it * 16 + br) * N + bn + bc * 8);
    }
    __syncthreads();
#pragma unroll
    for (int it = 0; it < 2; it++) {
      *(bf16x8*)&lA[(size_t)(it * 256 + tid) * 8] = va[it];
      *(bf16x8*)&lBn[(size_t)(it * 256 + tid) * 8] = vb[it];
    }
    __syncthreads();
    bf16x8 af[4], bfr[4];
#pragma unroll
    for (int m = 0; m < 4; m++) af[m] = *(const bf16x8*)&lA[(wr + m * 16 + l15) * 32 + lg * 8];
#pragma unroll
    for (int n = 0; n < 4; n++) {
#pragma unroll
      for (int j = 0; j < 8; j++)
        ((short*)&bfr[n])[j] = (short)lBn[(lg * 8 + j) * 128 + wc + n * 16 + l15];
    }
#pragma unroll
    for (int m = 0; m < 4; m++)
#pragma unroll
      for (int n = 0; n < 4; n++) acc[m][n] = mfma16(af[m], bfr[n], acc[m][n]);
  }
#pragma unroll
  for (int n = 0; n < 4; n++) {
    int col = bn + wc + n * 16 + l15;
    float bv = bias[col];
#pragma unroll
    for (int m = 0; m < 4; m++) {
#pragma unroll
      for (int r = 0; r < 4; r++) {
        int row = bm + wr + m * 16 + lg * 4 + r;
        out[(size_t)row * N + col] = acc[m][n][r] + bv;
      }
    }
  }
}

// ---------- fused flash attention, no-max softmax, K-tile register prefetch ----------
template <bool CAUSAL>
__global__ __launch_bounds__(256) void attn_k(const u16* __restrict__ Qb, const u16* __restrict__ Kb,
                                              const u16* __restrict__ Vtb, const float* __restrict__ R,
                                              float* __restrict__ Ob) {
  int bh = blockIdx.y;
  int tid = threadIdx.x, lane = tid & 63, w = tid >> 6;
  int l15 = lane & 15, lg = lane >> 4;
  int q0 = blockIdx.x * 64 + w * 16;
  const u16* Qh = Qb + (size_t)bh * 512 * 64;
  const u16* Kh = Kb + (size_t)bh * 512 * 64;
  const u16* Vh = Vtb + (size_t)bh * 64 * 512;
  __shared__ __align__(16) u16 P[4][16 * 40];
  u16* Pw = &P[w][0];
  bf16x8 qa0 = *(const bf16x8*)&Qh[(size_t)(q0 + l15) * 64 + lg * 8];
  bf16x8 qa1 = *(const bf16x8*)&Qh[(size_t)(q0 + l15) * 64 + 32 + lg * 8];
  f32x4 acc[4];
#pragma unroll
  for (int c = 0; c < 4; c++) acc[c] = (f32x4){0.f, 0.f, 0.f, 0.f};
  float ls[4] = {0.f, 0.f, 0.f, 0.f};
  int ktend = CAUSAL ? ((q0 + 15) >> 5) : 15;
  bf16x8 kn00 = *(const bf16x8*)&Kh[(size_t)(l15) * 64 + lg * 8];
  bf16x8 kn01 = *(const bf16x8*)&Kh[(size_t)(l15) * 64 + 32 + lg * 8];
  bf16x8 kn10 = *(const bf16x8*)&Kh[(size_t)(16 + l15) * 64 + lg * 8];
  bf16x8 kn11 = *(const bf16x8*)&Kh[(size_t)(16 + l15) * 64 + 32 + lg * 8];
  for (int kt = 0; kt <= ktend; kt++) {
    int kv = kt * 32;
    bf16x8 c00 = kn00, c01 = kn01, c10 = kn10, c11 = kn11;
    if (kt < ktend) {
      int kv2 = kv + 32;
      kn00 = *(const bf16x8*)&Kh[(size_t)(kv2 + l15) * 64 + lg * 8];
      kn01 = *(const bf16x8*)&Kh[(size_t)(kv2 + l15) * 64 + 32 + lg * 8];
      kn10 = *(const bf16x8*)&Kh[(size_t)(kv2 + 16 + l15) * 64 + lg * 8];
      kn11 = *(const bf16x8*)&Kh[(size_t)(kv2 + 16 + l15) * 64 + 32 + lg * 8];
    }
    f32x4 z = (f32x4){0.f, 0.f, 0.f, 0.f};
    f32x4 s0 = mfma16(qa0, c00, z);
    s0 = mfma16(qa1, c01, s0);
    f32x4 s1 = mfma16(qa0, c10, z);
    s1 = mfma16(qa1, c11, s1);
#pragma unroll
    for (int r = 0; r < 4; r++) {
      float a0 = s0[r] * 0.125f, a1 = s1[r] * 0.125f;
      if (CAUSAL) {
        int rowg = q0 + lg * 4 + r;
        if (kv + l15 > rowg) a0 = -1e30f;
        if (kv + 16 + l15 > rowg) a1 = -1e30f;
      }
      float p0 = __expf(a0), p1 = __expf(a1);
      ls[r] += p0 + p1;
      int prow = lg * 4 + r;
      Pw[prow * 40 + l15] = f2b(p0);
      Pw[prow * 40 + 16 + l15] = f2b(p1);
    }
    bf16x8 pa = *(const bf16x8*)&Pw[l15 * 40 + lg * 8];
#pragma unroll
    for (int c = 0; c < 4; c++) {
      bf16x8 vb = *(const bf16x8*)&Vh[(size_t)(c * 16 + l15) * 512 + kv + lg * 8];
      acc[c] = mfma16(pa, vb, acc[c]);
    }
  }
#pragma unroll
  for (int r = 0; r < 4; r++) {
#pragma unroll
    for (int off = 1; off < 16; off <<= 1) ls[r] += __shfl_xor(ls[r], off);
  }
  int b = bh >> 4, h = bh & 15;
#pragma unroll
  for (int r = 0; r < 4; r++) {
    float inv = 1.f / ls[r];
    int rowg = q0 + lg * 4 + r;
    size_t off0 = (size_t)(b * 512 + rowg) * 1024 + h * 64;
#pragma unroll
    for (int c = 0; c < 4; c++)
      Ob[off0 + c * 16 + l15] = R[off0 + c * 16 + l15] + acc[c][r] * inv;
  }
}

// ------------------------------- launch -------------------------------
extern "C" void kernel_launch(void* const* d_in, const int* in_sizes, int n_in,
                              void* d_out, int out_size, void* d_ws, size_t ws_size,
                              hipStream_t stream) {
  const int* fr = (const int*)d_in[0];
  const int* en = (const int*)d_in[1];
  const float* emb_fr = (const float*)d_in[2];
  const float* emb_en = (const float*)d_in[3];
  const float* enc_qkv_w = (const float*)d_in[4];
  const float* enc_qkv_b = (const float*)d_in[5];
  const float* enc_fc1_w = (const float*)d_in[6];
  const float* enc_fc1_b = (const float*)d_in[7];
  const float* enc_fc2_w = (const float*)d_in[8];
  const float* enc_fc2_b = (const float*)d_in[9];
  const float* enc_ln_g = (const float*)d_in[10];
  const float* enc_ln_bb = (const float*)d_in[11];
  const float* dec_self_qkv_w = (const float*)d_in[12];
  const float* dec_self_qkv_b = (const float*)d_in[13];
  const float* dec_cross_qkv_w = (const float*)d_in[14];
  const float* dec_cross_qkv_b = (const float*)d_in[15];
  const float* dec_fc1_w = (const float*)d_in[16];
  const float* dec_fc1_b = (const float*)d_in[17];
  const float* dec_fc2_w = (const float*)d_in[18];
  const float* dec_fc2_b = (const float*)d_in[19];
  const float* dec_ln_g = (const float*)d_in[20];
  const float* dec_ln_bb = (const float*)d_in[21];
  const float* out_w = (const float*)d_in[22];
  const float* out_b = (const float*)d_in[23];

  // scratch inside d_out (final GEMM reads only yb/outwT in d_ws, overwrites d_out)
  char* o8 = (char*)d_out;
  u16* qkvT_d = (u16*)o8;
  u16* fcT_d = (u16*)(o8 + 6291456);
  float* x32 = (float*)(o8 + 8388608);
  float* y32 = (float*)(o8 + 12582912);
  float* d32 = (float*)(o8 + 16777216);
  u16* xb = (u16*)(o8 + 20971520);
  u16* hb = (u16*)(o8 + 23068672);
  u16* Qb = (u16*)(o8 + 25165824);
  u16* Kb = (u16*)(o8 + 27262976);
  u16* Vtb = (u16*)(o8 + 29360128);

  // ws tiers
  char* w8 = (char*)d_ws;
  u16* yb = (u16*)w8;
  u16* outwT = (u16*)(w8 + 2097152);
  u16* eqkvT = (u16*)(w8 + 67633152);
  u16* dsqkvT = (u16*)(w8 + 92798976);
  u16* dcqkvT = (u16*)(w8 + 117964800);
  u16* efc1T = (u16*)(w8 + 143130624);
  u16* efc2T = (u16*)(w8 + 151519232);
  u16* dfc1T = (u16*)(w8 + 159907840);
  u16* dfc2T = (u16*)(w8 + 168296448);
  int tier = (ws_size >= 176685056u) ? 2 : (ws_size >= 67633152u) ? 1 : 0;

  dim3 tb(32, 8);
  if (tier >= 1)
    transpose_w<<<dim3(32, 1000, 1), tb, 0, stream>>>(out_w, outwT, 1024, 32000);
  if (tier == 2) {
    transpose_qkvT<<<dim3(32, 2, 576), tb, 0, stream>>>(enc_qkv_w, dec_self_qkv_w, dec_cross_qkv_w, eqkvT);
    transpose_fcT<<<dim3(32, 32, 16), tb, 0, stream>>>(enc_fc1_w, enc_fc2_w, dec_fc1_w, dec_fc2_w, efc1T);
  }

  embed_k<<<1024, 256, 0, stream>>>(fr, emb_fr, x32, xb, 1);
  embed_k<<<1024, 256, 0, stream>>>(en, emb_en, y32, yb, 0);

  // encoder
  for (int n = 0; n < 4; n++) {
    const u16* wqkv;
    if (tier == 2) wqkv = eqkvT + (size_t)n * 3145728;
    else {
      transpose_w<<<dim3(32, 2, 48), tb, 0, stream>>>(enc_qkv_w + (size_t)n * 48 * 65536, qkvT_d, 1024, 64);
      wqkv = qkvT_d;
    }
    gemm_qkv3<<<dim3(48, 16), 256, 0, stream>>>(xb, xb, wqkv, enc_qkv_b + (size_t)n * 3072, Qb, Kb, Vtb);
    attn_k<false><<<dim3(8, 32), 256, 0, stream>>>(Qb, Kb, Vtb, x32, d32);
    ln_k<<<1024, 256, 0, stream>>>(d32, enc_ln_g + (size_t)(n * 2) * 1024,
                                   enc_ln_bb + (size_t)(n * 2) * 1024, x32, xb);
    const u16* w1;
    if (tier == 2) w1 = efc1T + (size_t)n * 1048576;
    else {
      transpose_w<<<dim3(32, 32, 1), tb, 0, stream>>>(enc_fc1_w + (size_t)n * 1048576, fcT_d, 1024, 1024);
      w1 = fcT_d;
    }
    gemm_fc<true><<<dim3(16, 16), 256, 0, stream>>>(xb, w1, enc_fc1_b + (size_t)n * 1024,
                                                    nullptr, hb, 1024, 1024);
    const u16* w2;
    if (tier == 2) w2 = efc2T + (size_t)n * 1048576;
    else {
      transpose_w<<<dim3(32, 32, 1), tb, 0, stream>>>(enc_fc2_w + (size_t)n * 1048576, fcT_d, 1024, 1024);
      w2 = fcT_d;
    }
    gemm_fc<false><<<dim3(16, 16), 256, 0, stream>>>(hb, w2, enc_fc2_b + (size_t)n * 1024,
                                                     x32, d32, 1024, 1024);
    ln_k<<<1024, 256, 0, stream>>>(d32, enc_ln_g + (size_t)(n * 2 + 1) * 1024,
                                   enc_ln_bb + (size_t)(n * 2 + 1) * 1024, x32, xb);
  }
  // decoder (enc_out lives in xb)
  for (int n = 0; n < 4; n++) {
    const u16* wq;
    if (tier == 2) wq = dsqkvT + (size_t)n * 3145728;
    else {
      transpose_w<<<dim3(32, 2, 48), tb, 0, stream>>>(dec_self_qkv_w + (size_t)n * 48 * 65536, qkvT_d, 1024, 64);
      wq = qkvT_d;
    }
    gemm_qkv3<<<dim3(48, 16), 256, 0, stream>>>(yb, yb, wq, dec_self_qkv_b + (size_t)n * 3072, Qb, Kb, Vtb);
    attn_k<true><<<dim3(8, 32), 256, 0, stream>>>(Qb, Kb, Vtb, y32, d32);
    ln_k<<<1024, 256, 0, stream>>>(d32, dec_ln_g + (size_t)(n * 3) * 1024,
                                   dec_ln_bb + (size_t)(n * 3) * 1024, y32, yb);
    if (tier == 2) wq = dcqkvT + (size_t)n * 3145728;
    else {
      transpose_w<<<dim3(32, 2, 48), tb, 0, stream>>>(dec_cross_qkv_w + (size_t)n * 48 * 65536, qkvT_d, 1024, 64);
      wq = qkvT_d;
    }
    gemm_qkv3<<<dim3(48, 16), 256, 0, stream>>>(yb, xb, wq, dec_cross_qkv_b + (size_t)n * 3072, Qb, Kb, Vtb);
    attn_k<false><<<dim3(8, 32), 256, 0, stream>>>(Qb, Kb, Vtb, y32, d32);
    ln_k<<<1024, 256, 0, stream>>>(d32, dec_ln_g + (size_t)(n * 3 + 1) * 1024,
                                   dec_ln_bb + (size_t)(n * 3 + 1) * 1024, y32, yb);
    const u16* w1;
    if (tier == 2) w1 = dfc1T + (size_t)n * 1048576;
    else {
      transpose_w<<<dim3(32, 32, 1), tb, 0, stream>>>(dec_fc1_w + (size_t)n * 1048576, fcT_d, 1024, 1024);
      w1 = fcT_d;
    }
    gemm_fc<true><<<dim3(16, 16), 256, 0, stream>>>(yb, w1, dec_fc1_b + (size_t)n * 1024,
                                                    nullptr, hb, 1024, 1024);
    const u16* w2;
    if (tier == 2) w2 = dfc2T + (size_t)n * 1048576;
    else {
      transpose_w<<<dim3(32, 32, 1), tb, 0, stream>>>(dec_fc2_w + (size_t)n * 1048576, fcT_d, 1024, 1024);
      w2 = fcT_d;
    }
    gemm_fc<false><<<dim3(16, 16), 256, 0, stream>>>(hb, w2, dec_fc2_b + (size_t)n * 1024,
                                                     y32, d32, 1024, 1024);
    ln_k<<<1024, 256, 0, stream>>>(d32, dec_ln_g + (size_t)(n * 3 + 2) * 1024,
                                   dec_ln_bb + (size_t)(n * 3 + 2) * 1024, y32, yb);
  }
  // final projection -> d_out (f32); reads only yb/outwT (in d_ws)
  if (tier >= 1)
    gemm_f256<<<dim3(512), 512, 0, stream>>>(yb, outwT, out_b, (float*)d_out, 32000, 1024);
  else
    gemm_bn<<<dim3(2048), 256, 0, stream>>>(yb, out_w, out_b, (float*)d_out, 32000, 1024);
}

// Round 15
// 953.386 us; speedup vs baseline: 1.0093x; 1.0093x over previous
//
#include <hip/hip_runtime.h>
#include <stdint.h>
#include <stddef.h>

typedef unsigned short u16;
typedef __attribute__((ext_vector_type(8))) short bf16x8;
typedef __attribute__((ext_vector_type(4))) float f32x4;

#define DEV __device__ __forceinline__

DEV float b2f(u16 u) { union { float f; uint32_t i; } v; v.i = ((uint32_t)u) << 16; return v.f; }
DEV u16 f2b(float f) {
  uint32_t x = __float_as_uint(f);
  x += 0x7fffu + ((x >> 16) & 1u);
  return (u16)(x >> 16);
}
DEV bf16x8 ld8f(const float* f) {
  float4 a = *(const float4*)f;
  float4 b = *(const float4*)(f + 4);
  bf16x8 r;
  ((u16*)&r)[0] = f2b(a.x); ((u16*)&r)[1] = f2b(a.y);
  ((u16*)&r)[2] = f2b(a.z); ((u16*)&r)[3] = f2b(a.w);
  ((u16*)&r)[4] = f2b(b.x); ((u16*)&r)[5] = f2b(b.y);
  ((u16*)&r)[6] = f2b(b.z); ((u16*)&r)[7] = f2b(b.w);
  return r;
}
DEV void gload16(const u16* g, u16* l) {
  __builtin_amdgcn_global_load_lds((const __attribute__((address_space(1))) void*)g,
                                   (__attribute__((address_space(3))) void*)l, 16, 0, 0);
}
DEV f32x4 mfma16(bf16x8 a, bf16x8 b, f32x4 c) {
  return __builtin_amdgcn_mfma_f32_16x16x32_bf16(a, b, c, 0, 0, 0);
}

// ---------- transpose f32 [K][N] -> bf16 [N][K], batched over z (tier0/1 path) ----------
__global__ __launch_bounds__(256) void transpose_w(const float* __restrict__ src,
                                                   u16* __restrict__ dst, int K, int N) {
  __shared__ u16 t[32][33];
  int tx = threadIdx.x, ty = threadIdx.y;
  int k0 = blockIdx.x * 32, n0 = blockIdx.y * 32;
  size_t base = (size_t)blockIdx.z * K * N;
#pragma unroll
  for (int i = 0; i < 4; i++) {
    int k = ty + 8 * i;
    t[k][tx] = f2b(src[base + (size_t)(k0 + k) * N + n0 + tx]);
  }
  __syncthreads();
#pragma unroll
  for (int i = 0; i < 4; i++) {
    int n = ty + 8 * i;
    dst[base + (size_t)(n0 + n) * K + k0 + tx] = t[tx][n];
  }
}

// ---------- merged QKV weight transpose: 3 tensors x 192 [1024][64] -> [N][K] bf16 ----------
__global__ __launch_bounds__(256) void transpose_qkvT(const float* __restrict__ s0,
                                                      const float* __restrict__ s1,
                                                      const float* __restrict__ s2,
                                                      u16* __restrict__ dst) {
  int z = blockIdx.z;
  const float* src = (z < 192) ? s0 : (z < 384) ? s1 : s2;
  int zi = (z < 192) ? z : (z < 384) ? z - 192 : z - 384;
  size_t sbase = (size_t)zi * 65536;
  size_t dbase = (size_t)z * 65536;
  __shared__ u16 t[32][33];
  int tx = threadIdx.x, ty = threadIdx.y;
  int k0 = blockIdx.x * 32, n0 = blockIdx.y * 32;
#pragma unroll
  for (int i = 0; i < 4; i++) {
    int k = ty + 8 * i;
    t[k][tx] = f2b(src[sbase + (size_t)(k0 + k) * 64 + n0 + tx]);
  }
  __syncthreads();
#pragma unroll
  for (int i = 0; i < 4; i++) {
    int n = ty + 8 * i;
    dst[dbase + (size_t)(n0 + n) * 1024 + k0 + tx] = t[tx][n];
  }
}

// ---------- merged FC weight transpose: 4 tensors x 4 layers [1024][1024] ----------
__global__ __launch_bounds__(256) void transpose_fcT(const float* __restrict__ s0,
                                                     const float* __restrict__ s1,
                                                     const float* __restrict__ s2,
                                                     const float* __restrict__ s3,
                                                     u16* __restrict__ dst) {
  int z = blockIdx.z;
  const float* src = (z < 4) ? s0 : (z < 8) ? s1 : (z < 12) ? s2 : s3;
  size_t sbase = (size_t)(z & 3) * 1048576;
  size_t dbase = (size_t)z * 1048576;
  __shared__ u16 t[32][33];
  int tx = threadIdx.x, ty = threadIdx.y;
  int k0 = blockIdx.x * 32, n0 = blockIdx.y * 32;
#pragma unroll
  for (int i = 0; i < 4; i++) {
    int k = ty + 8 * i;
    t[k][tx] = f2b(src[sbase + (size_t)(k0 + k) * 1024 + n0 + tx]);
  }
  __syncthreads();
#pragma unroll
  for (int i = 0; i < 4; i++) {
    int n = ty + 8 * i;
    dst[dbase + (size_t)(n0 + n) * 1024 + k0 + tx] = t[tx][n];
  }
}

// ---------- embedding gather + sinusoidal positional encoding ----------
__global__ __launch_bounds__(256) void embed_k(const int* __restrict__ tok, const float* __restrict__ emb,
                                               float* __restrict__ o32, u16* __restrict__ ob, int shift) {
  int row = blockIdx.x;
  int b = row >> 9, l = row & 511;
  int tk = tok[(size_t)(l + shift) * 2 + b];
  const float* e = emb + (size_t)tk * 1024;
  const float c0 = -9.210340371976184f / 1024.f;
#pragma unroll
  for (int i = 0; i < 4; i++) {
    int d = threadIdx.x + i * 256;
    int j2 = d & ~1;
    float ang = (float)l * expf(c0 * (float)j2);
    float pe = (d & 1) ? cosf(ang) : sinf(ang);
    float rv = e[d] + pe;
    o32[(size_t)row * 1024 + d] = rv;
    ob[(size_t)row * 1024 + d] = f2b(rv);
  }
}

// ---------- LayerNorm (input d already includes residual), fp32 in, fp32+bf16 out ----------
__global__ __launch_bounds__(256) void ln_k(const float* d,
                                            const float* __restrict__ g, const float* __restrict__ bb,
                                            float* o32, u16* __restrict__ ob) {
  int row = blockIdx.x;
  int tid = threadIdx.x;
  const float4 dv = ((const float4*)(d + (size_t)row * 1024))[tid];
  float v[4] = {dv.x, dv.y, dv.z, dv.w};
  float s = 0.f, s2 = 0.f;
#pragma unroll
  for (int i = 0; i < 4; i++) { s += v[i]; s2 += v[i] * v[i]; }
#pragma unroll
  for (int off = 1; off < 64; off <<= 1) {
    s += __shfl_xor(s, off);
    s2 += __shfl_xor(s2, off);
  }
  __shared__ float red[8];
  int wid = tid >> 6;
  if ((tid & 63) == 0) { red[wid * 2] = s; red[wid * 2 + 1] = s2; }
  __syncthreads();
  s = red[0] + red[2] + red[4] + red[6];
  s2 = red[1] + red[3] + red[5] + red[7];
  float mu = s * (1.f / 1024.f);
  float var = s2 * (1.f / 1024.f) - mu * mu;
  float inv = rsqrtf(var + 1e-5f);
  const float4 gv = ((const float4*)g)[tid];
  const float4 bv = ((const float4*)bb)[tid];
  float4 ov;
  ov.x = (v[0] - mu) * inv * gv.x + bv.x;
  ov.y = (v[1] - mu) * inv * gv.y + bv.y;
  ov.z = (v[2] - mu) * inv * gv.z + bv.z;
  ov.w = (v[3] - mu) * inv * gv.w + bv.w;
  ((float4*)(o32 + (size_t)row * 1024))[tid] = ov;
  uint2 p;
  p.x = (uint32_t)f2b(ov.x) | ((uint32_t)f2b(ov.y) << 16);
  p.y = (uint32_t)f2b(ov.z) | ((uint32_t)f2b(ov.w) << 16);
  ((uint2*)(ob + (size_t)row * 1024))[tid] = p;
}

// ---------- FFN GEMM: 64x64 tile, BK=64, depth-2 counted-vmcnt pipeline ----------
template <bool RELU>
__global__ __launch_bounds__(256) void gemm_fc(const u16* __restrict__ A, const u16* __restrict__ BT,
                                               const float* __restrict__ bias,
                                               const float* __restrict__ resid, void* __restrict__ out,
                                               int N, int K) {
  __shared__ __align__(16) u16 lA[2][2][64 * 32];
  __shared__ __align__(16) u16 lB[2][2][64 * 32];
  int bx = blockIdx.x, by = blockIdx.y;
  int tid = threadIdx.x, lane = tid & 63, wid = tid >> 6;
  int l15 = lane & 15, lg = lane >> 4;
  int bm = by * 64, bn = bx * 64;
  int wr = (wid >> 1) * 32, wc = (wid & 1) * 32;
  f32x4 acc[2][2] = {};
  int r_s = tid >> 2, c_s = tid & 3;
  auto stage = [&](int pp, int kt) {
#pragma unroll
    for (int s = 0; s < 2; s++) {
      gload16(A + (size_t)(bm + r_s) * K + kt + s * 32 + c_s * 8, &lA[pp][s][(size_t)(wid * 64) * 8]);
      gload16(BT + (size_t)(bn + r_s) * K + kt + s * 32 + c_s * 8, &lB[pp][s][(size_t)(wid * 64) * 8]);
    }
  };
  int nt = K >> 6;
  stage(0, 0);
  int pp = 0;
  for (int t = 0; t < nt; t++) {
    if (t + 1 < nt) {
      stage(pp ^ 1, (t + 1) * 64);
      asm volatile("s_waitcnt vmcnt(4)" ::: "memory");
    } else {
      asm volatile("s_waitcnt vmcnt(0)" ::: "memory");
    }
    __builtin_amdgcn_s_barrier();
#pragma unroll
    for (int s = 0; s < 2; s++) {
      bf16x8 af[2], bf_[2];
#pragma unroll
      for (int m = 0; m < 2; m++) af[m] = *(const bf16x8*)&lA[pp][s][(wr + m * 16 + l15) * 32 + lg * 8];
#pragma unroll
      for (int n = 0; n < 2; n++) bf_[n] = *(const bf16x8*)&lB[pp][s][(wc + n * 16 + l15) * 32 + lg * 8];
#pragma unroll
      for (int m = 0; m < 2; m++)
#pragma unroll
        for (int n = 0; n < 2; n++) acc[m][n] = mfma16(af[m], bf_[n], acc[m][n]);
    }
    __builtin_amdgcn_s_barrier();
    pp ^= 1;
  }
#pragma unroll
  for (int n = 0; n < 2; n++) {
    int col = bn + wc + n * 16 + l15;
    float bv = bias[col];
#pragma unroll
    for (int m = 0; m < 2; m++) {
#pragma unroll
      for (int r = 0; r < 4; r++) {
        int row = bm + wr + m * 16 + lg * 4 + r;
        float v = acc[m][n][r] + bv;
        if (RELU) ((u16*)out)[(size_t)row * N + col] = f2b(fmaxf(v, 0.f));
        else ((float*)out)[(size_t)row * N + col] = v + resid[(size_t)row * N + col];
      }
    }
  }
}

// ---------- fused QKV projection, 64x64 tiles, BK=64, depth-2 pipeline ----------
__global__ __launch_bounds__(256) void gemm_qkv3(const u16* __restrict__ Aq, const u16* __restrict__ Akv,
                                                 const u16* __restrict__ WT, const float* __restrict__ bias,
                                                 u16* __restrict__ Qo, u16* __restrict__ Ko,
                                                 u16* __restrict__ Vto) {
  __shared__ __align__(16) u16 lA[2][2][64 * 32];
  __shared__ __align__(16) u16 lB[2][2][64 * 32];
  int bx = blockIdx.x, by = blockIdx.y;
  int t_ = bx >> 4;
  const u16* A = (t_ == 0) ? Aq : Akv;
  int tid = threadIdx.x, lane = tid & 63, wid = tid >> 6;
  int l15 = lane & 15, lg = lane >> 4;
  int bm = by * 64, bn = bx * 64;
  int wr = (wid >> 1) * 32, wc = (wid & 1) * 32;
  f32x4 acc[2][2] = {};
  int r_s = tid >> 2, c_s = tid & 3;
  auto stage = [&](int pp, int kt) {
#pragma unroll
    for (int s = 0; s < 2; s++) {
      gload16(A + (size_t)(bm + r_s) * 1024 + kt + s * 32 + c_s * 8, &lA[pp][s][(size_t)(wid * 64) * 8]);
      gload16(WT + (size_t)(bn + r_s) * 1024 + kt + s * 32 + c_s * 8, &lB[pp][s][(size_t)(wid * 64) * 8]);
    }
  };
  stage(0, 0);
  int pp = 0;
  for (int t = 0; t < 16; t++) {
    if (t + 1 < 16) {
      stage(pp ^ 1, (t + 1) * 64);
      asm volatile("s_waitcnt vmcnt(4)" ::: "memory");
    } else {
      asm volatile("s_waitcnt vmcnt(0)" ::: "memory");
    }
    __builtin_amdgcn_s_barrier();
#pragma unroll
    for (int s = 0; s < 2; s++) {
      bf16x8 af[2], bf_[2];
#pragma unroll
      for (int m = 0; m < 2; m++) af[m] = *(const bf16x8*)&lA[pp][s][(wr + m * 16 + l15) * 32 + lg * 8];
#pragma unroll
      for (int n = 0; n < 2; n++) bf_[n] = *(const bf16x8*)&lB[pp][s][(wc + n * 16 + l15) * 32 + lg * 8];
#pragma unroll
      for (int m = 0; m < 2; m++)
#pragma unroll
        for (int n = 0; n < 2; n++) acc[m][n] = mfma16(af[m], bf_[n], acc[m][n]);
    }
    __builtin_amdgcn_s_barrier();
    pp ^= 1;
  }
#pragma unroll
  for (int n = 0; n < 2; n++) {
    int col = bn + wc + n * 16 + l15;
    int h = (col >> 6) & 15, e = col & 63;
    float bv = bias[col];
#pragma unroll
    for (int m = 0; m < 2; m++) {
#pragma unroll
      for (int r = 0; r < 4; r++) {
        int row = bm + wr + m * 16 + lg * 4 + r;
        int b = row >> 9, l = row & 511;
        u16 vbv = f2b(acc[m][n][r] + bv);
        size_t bhead = (size_t)b * 16 + h;
        if (t_ == 0) Qo[(bhead * 512 + l) * 64 + e] = vbv;
        else if (t_ == 1) Ko[(bhead * 512 + l) * 64 + e] = vbv;
        else Vto[(bhead * 64 + e) * 512 + l] = vbv;
      }
    }
  }
}

// ---------- final projection: 256x256 tile, 8 waves, BK=64, depth-2 counted-vmcnt ----------
// One full iteration (~64 MFMA/wave) between stage(t) issue and its vmcnt wait ->
// load latency fully covered. LDS 128 KB (2 dbuf x (256x64 A + 256x64 B) bf16), 1 block/CU.
// Grid 512 (1D); bijective panel-per-XCD swizzle: p=(b&7)+8*(b>>5) [guard >=125], row=(b>>3)&3.
__global__ __launch_bounds__(512) void gemm_f256(const u16* __restrict__ A, const u16* __restrict__ BT,
                                                 const float* __restrict__ bias, float* __restrict__ out,
                                                 int N, int K) {
  __shared__ __align__(16) u16 lA[2][256 * 64];
  __shared__ __align__(16) u16 lB[2][256 * 64];
  int b = blockIdx.x;
  int p = (b & 7) + 8 * (b >> 5);
  if (p >= N / 256) return;
  int brow = (b >> 3) & 3;
  int tid = threadIdx.x, lane = tid & 63, wid = tid >> 6;
  int l15 = lane & 15, lg = lane >> 4;
  int bm = brow * 256, bn = p * 256;
  int wrow = (wid >> 2) * 128, wcol = (wid & 3) * 64;  // 8 waves = 2M x 4N; per wave 128x64
  f32x4 acc[8][4] = {};
  auto stage = [&](int pp, int kt) {
#pragma unroll
    for (int i = 0; i < 4; i++) {  // A: 256 rows x 64 k, 2048 chunks of 8 u16
      int c = i * 512 + tid;
      int row = c >> 3, kc = c & 7;
      gload16(A + (size_t)(bm + row) * K + kt + kc * 8, &lA[pp][(size_t)c * 8]);
    }
#pragma unroll
    for (int i = 0; i < 4; i++) {
      int c = i * 512 + tid;
      int row = c >> 3, kc = c & 7;
      gload16(BT + (size_t)(bn + row) * K + kt + kc * 8, &lB[pp][(size_t)c * 8]);
    }
  };
  int nt = K >> 6;  // 16
  stage(0, 0);
  int pp = 0;
  for (int t = 0; t < nt; t++) {
    if (t + 1 < nt) {
      stage(pp ^ 1, (t + 1) * 64);
      asm volatile("s_waitcnt vmcnt(8)" ::: "memory");  // stage t landed; t+1's 8 in flight
    } else {
      asm volatile("s_waitcnt vmcnt(0)" ::: "memory");
    }
    __builtin_amdgcn_s_barrier();
#pragma unroll
    for (int kk = 0; kk < 2; kk++) {
      bf16x8 af[8], bf_[4];
#pragma unroll
      for (int m = 0; m < 8; m++)
        af[m] = *(const bf16x8*)&lA[pp][(wrow + m * 16 + l15) * 64 + kk * 32 + lg * 8];
#pragma unroll
      for (int n = 0; n < 4; n++)
        bf_[n] = *(const bf16x8*)&lB[pp][(wcol + n * 16 + l15) * 64 + kk * 32 + lg * 8];
#pragma unroll
      for (int m = 0; m < 8; m++)
#pragma unroll
        for (int n = 0; n < 4; n++) acc[m][n] = mfma16(af[m], bf_[n], acc[m][n]);
    }
    __builtin_amdgcn_s_barrier();
    pp ^= 1;
  }
#pragma unroll
  for (int n = 0; n < 4; n++) {
    int col = bn + wcol + n * 16 + l15;
    float bv = bias[col];
#pragma unroll
    for (int m = 0; m < 8; m++) {
#pragma unroll
      for (int r = 0; r < 4; r++) {
        int row = bm + wrow + m * 16 + lg * 4 + r;
        out[(size_t)row * N + col] = acc[m][n][r] + bv;
      }
    }
  }
}

// ---------- fallback final projection (tier0): A bf16; B f32 [K][N]; out f32 ----------
__global__ __launch_bounds__(256) void gemm_bn(const u16* __restrict__ A, const float* __restrict__ B,
                                               const float* __restrict__ bias, float* __restrict__ out,
                                               int N, int K) {
  __shared__ __align__(16) u16 lA[128 * 32];
  __shared__ __align__(16) u16 lBn[32 * 128];
  int b = blockIdx.x;
  int p = (b & 7) + 8 * (b >> 6);
  if (p >= N / 128) return;
  int by = (b >> 3) & 7;
  int tid = threadIdx.x, lane = tid & 63;
  int wid = tid >> 6;
  int l15 = lane & 15, lg = lane >> 4;
  int bm = by * 128, bn = p * 128;
  int wr = (wid >> 1) * 64, wc = (wid & 1) * 64;
  f32x4 acc[4][4] = {};
  int r_s = tid >> 2, c_s = tid & 3;
  int br = tid >> 4, bc = tid & 15;
  for (int kt = 0; kt < K; kt += 32) {
    bf16x8 va[2], vb[2];
#pragma unroll
    for (int it = 0; it < 2; it++) {
      va[it] = *(const bf16x8*)&A[(size_t)(bm + it * 64 + r_s) * K + kt + c_s * 8];
      vb[it] = ld8f(B + (size_t)(kt + it * 16 + br) * N + bn + bc * 8);
    }
    __syncthreads();
#pragma unroll
    for (int it = 0; it < 2; it++) {
      *(bf16x8*)&lA[(size_t)(it * 256 + tid) * 8] = va[it];
      *(bf16x8*)&lBn[(size_t)(it * 256 + tid) * 8] = vb[it];
    }
    __syncthreads();
    bf16x8 af[4], bfr[4];
#pragma unroll
    for (int m = 0; m < 4; m++) af[m] = *(const bf16x8*)&lA[(wr + m * 16 + l15) * 32 + lg * 8];
#pragma unroll
    for (int n = 0; n < 4; n++) {
#pragma unroll
      for (int j = 0; j < 8; j++)
        ((short*)&bfr[n])[j] = (short)lBn[(lg * 8 + j) * 128 + wc + n * 16 + l15];
    }
#pragma unroll
    for (int m = 0; m < 4; m++)
#pragma unroll
      for (int n = 0; n < 4; n++) acc[m][n] = mfma16(af[m], bfr[n], acc[m][n]);
  }
#pragma unroll
  for (int n = 0; n < 4; n++) {
    int col = bn + wc + n * 16 + l15;
    float bv = bias[col];
#pragma unroll
    for (int m = 0; m < 4; m++) {
#pragma unroll
      for (int r = 0; r < 4; r++) {
        int row = bm + wr + m * 16 + lg * 4 + r;
        out[(size_t)row * N + col] = acc[m][n][r] + bv;
      }
    }
  }
}

// ---------- fused flash attention, no-max softmax, K-tile register prefetch ----------
template <bool CAUSAL>
__global__ __launch_bounds__(256) void attn_k(const u16* __restrict__ Qb, const u16* __restrict__ Kb,
                                              const u16* __restrict__ Vtb, const float* __restrict__ R,
                                              float* __restrict__ Ob) {
  int bh = blockIdx.y;
  int tid = threadIdx.x, lane = tid & 63, w = tid >> 6;
  int l15 = lane & 15, lg = lane >> 4;
  int q0 = blockIdx.x * 64 + w * 16;
  const u16* Qh = Qb + (size_t)bh * 512 * 64;
  const u16* Kh = Kb + (size_t)bh * 512 * 64;
  const u16* Vh = Vtb + (size_t)bh * 64 * 512;
  __shared__ __align__(16) u16 P[4][16 * 40];
  u16* Pw = &P[w][0];
  bf16x8 qa0 = *(const bf16x8*)&Qh[(size_t)(q0 + l15) * 64 + lg * 8];
  bf16x8 qa1 = *(const bf16x8*)&Qh[(size_t)(q0 + l15) * 64 + 32 + lg * 8];
  f32x4 acc[4];
#pragma unroll
  for (int c = 0; c < 4; c++) acc[c] = (f32x4){0.f, 0.f, 0.f, 0.f};
  float ls[4] = {0.f, 0.f, 0.f, 0.f};
  int ktend = CAUSAL ? ((q0 + 15) >> 5) : 15;
  bf16x8 kn00 = *(const bf16x8*)&Kh[(size_t)(l15) * 64 + lg * 8];
  bf16x8 kn01 = *(const bf16x8*)&Kh[(size_t)(l15) * 64 + 32 + lg * 8];
  bf16x8 kn10 = *(const bf16x8*)&Kh[(size_t)(16 + l15) * 64 + lg * 8];
  bf16x8 kn11 = *(const bf16x8*)&Kh[(size_t)(16 + l15) * 64 + 32 + lg * 8];
  for (int kt = 0; kt <= ktend; kt++) {
    int kv = kt * 32;
    bf16x8 c00 = kn00, c01 = kn01, c10 = kn10, c11 = kn11;
    if (kt < ktend) {
      int kv2 = kv + 32;
      kn00 = *(const bf16x8*)&Kh[(size_t)(kv2 + l15) * 64 + lg * 8];
      kn01 = *(const bf16x8*)&Kh[(size_t)(kv2 + l15) * 64 + 32 + lg * 8];
      kn10 = *(const bf16x8*)&Kh[(size_t)(kv2 + 16 + l15) * 64 + lg * 8];
      kn11 = *(const bf16x8*)&Kh[(size_t)(kv2 + 16 + l15) * 64 + 32 + lg * 8];
    }
    f32x4 z = (f32x4){0.f, 0.f, 0.f, 0.f};
    f32x4 s0 = mfma16(qa0, c00, z);
    s0 = mfma16(qa1, c01, s0);
    f32x4 s1 = mfma16(qa0, c10, z);
    s1 = mfma16(qa1, c11, s1);
#pragma unroll
    for (int r = 0; r < 4; r++) {
      float a0 = s0[r] * 0.125f, a1 = s1[r] * 0.125f;
      if (CAUSAL) {
        int rowg = q0 + lg * 4 + r;
        if (kv + l15 > rowg) a0 = -1e30f;
        if (kv + 16 + l15 > rowg) a1 = -1e30f;
      }
      float p0 = __expf(a0), p1 = __expf(a1);
      ls[r] += p0 + p1;
      int prow = lg * 4 + r;
      Pw[prow * 40 + l15] = f2b(p0);
      Pw[prow * 40 + 16 + l15] = f2b(p1);
    }
    bf16x8 pa = *(const bf16x8*)&Pw[l15 * 40 + lg * 8];
#pragma unroll
    for (int c = 0; c < 4; c++) {
      bf16x8 vb = *(const bf16x8*)&Vh[(size_t)(c * 16 + l15) * 512 + kv + lg * 8];
      acc[c] = mfma16(pa, vb, acc[c]);
    }
  }
#pragma unroll
  for (int r = 0; r < 4; r++) {
#pragma unroll
    for (int off = 1; off < 16; off <<= 1) ls[r] += __shfl_xor(ls[r], off);
  }
  int b = bh >> 4, h = bh & 15;
#pragma unroll
  for (int r = 0; r < 4; r++) {
    float inv = 1.f / ls[r];
    int rowg = q0 + lg * 4 + r;
    size_t off0 = (size_t)(b * 512 + rowg) * 1024 + h * 64;
#pragma unroll
    for (int c = 0; c < 4; c++)
      Ob[off0 + c * 16 + l15] = R[off0 + c * 16 + l15] + acc[c][r] * inv;
  }
}

// ------------------------------- launch -------------------------------
extern "C" void kernel_launch(void* const* d_in, const int* in_sizes, int n_in,
                              void* d_out, int out_size, void* d_ws, size_t ws_size,
                              hipStream_t stream) {
  const int* fr = (const int*)d_in[0];
  const int* en = (const int*)d_in[1];
  const float* emb_fr = (const float*)d_in[2];
  const float* emb_en = (const float*)d_in[3];
  const float* enc_qkv_w = (const float*)d_in[4];
  const float* enc_qkv_b = (const float*)d_in[5];
  const float* enc_fc1_w = (const float*)d_in[6];
  const float* enc_fc1_b = (const float*)d_in[7];
  const float* enc_fc2_w = (const float*)d_in[8];
  const float* enc_fc2_b = (const float*)d_in[9];
  const float* enc_ln_g = (const float*)d_in[10];
  const float* enc_ln_bb = (const float*)d_in[11];
  const float* dec_self_qkv_w = (const float*)d_in[12];
  const float* dec_self_qkv_b = (const float*)d_in[13];
  const float* dec_cross_qkv_w = (const float*)d_in[14];
  const float* dec_cross_qkv_b = (const float*)d_in[15];
  const float* dec_fc1_w = (const float*)d_in[16];
  const float* dec_fc1_b = (const float*)d_in[17];
  const float* dec_fc2_w = (const float*)d_in[18];
  const float* dec_fc2_b = (const float*)d_in[19];
  const float* dec_ln_g = (const float*)d_in[20];
  const float* dec_ln_bb = (const float*)d_in[21];
  const float* out_w = (const float*)d_in[22];
  const float* out_b = (const float*)d_in[23];

  // scratch inside d_out (final GEMM reads only yb/outwT in d_ws, overwrites d_out)
  char* o8 = (char*)d_out;
  u16* qkvT_d = (u16*)o8;
  u16* fcT_d = (u16*)(o8 + 6291456);
  float* x32 = (float*)(o8 + 8388608);
  float* y32 = (float*)(o8 + 12582912);
  float* d32 = (float*)(o8 + 16777216);
  u16* xb = (u16*)(o8 + 20971520);
  u16* hb = (u16*)(o8 + 23068672);
  u16* Qb = (u16*)(o8 + 25165824);
  u16* Kb = (u16*)(o8 + 27262976);
  u16* Vtb = (u16*)(o8 + 29360128);

  // ws tiers
  char* w8 = (char*)d_ws;
  u16* yb = (u16*)w8;
  u16* outwT = (u16*)(w8 + 2097152);
  u16* eqkvT = (u16*)(w8 + 67633152);
  u16* dsqkvT = (u16*)(w8 + 92798976);
  u16* dcqkvT = (u16*)(w8 + 117964800);
  u16* efc1T = (u16*)(w8 + 143130624);
  u16* efc2T = (u16*)(w8 + 151519232);
  u16* dfc1T = (u16*)(w8 + 159907840);
  u16* dfc2T = (u16*)(w8 + 168296448);
  int tier = (ws_size >= 176685056u) ? 2 : (ws_size >= 67633152u) ? 1 : 0;

  dim3 tb(32, 8);
  if (tier >= 1)
    transpose_w<<<dim3(32, 1000, 1), tb, 0, stream>>>(out_w, outwT, 1024, 32000);
  if (tier == 2) {
    transpose_qkvT<<<dim3(32, 2, 576), tb, 0, stream>>>(enc_qkv_w, dec_self_qkv_w, dec_cross_qkv_w, eqkvT);
    transpose_fcT<<<dim3(32, 32, 16), tb, 0, stream>>>(enc_fc1_w, enc_fc2_w, dec_fc1_w, dec_fc2_w, efc1T);
  }

  embed_k<<<1024, 256, 0, stream>>>(fr, emb_fr, x32, xb, 1);
  embed_k<<<1024, 256, 0, stream>>>(en, emb_en, y32, yb, 0);

  // encoder
  for (int n = 0; n < 4; n++) {
    const u16* wqkv;
    if (tier == 2) wqkv = eqkvT + (size_t)n * 3145728;
    else {
      transpose_w<<<dim3(32, 2, 48), tb, 0, stream>>>(enc_qkv_w + (size_t)n * 48 * 65536, qkvT_d, 1024, 64);
      wqkv = qkvT_d;
    }
    gemm_qkv3<<<dim3(48, 16), 256, 0, stream>>>(xb, xb, wqkv, enc_qkv_b + (size_t)n * 3072, Qb, Kb, Vtb);
    attn_k<false><<<dim3(8, 32), 256, 0, stream>>>(Qb, Kb, Vtb, x32, d32);
    ln_k<<<1024, 256, 0, stream>>>(d32, enc_ln_g + (size_t)(n * 2) * 1024,
                                   enc_ln_bb + (size_t)(n * 2) * 1024, x32, xb);
    const u16* w1;
    if (tier == 2) w1 = efc1T + (size_t)n * 1048576;
    else {
      transpose_w<<<dim3(32, 32, 1), tb, 0, stream>>>(enc_fc1_w + (size_t)n * 1048576, fcT_d, 1024, 1024);
      w1 = fcT_d;
    }
    gemm_fc<true><<<dim3(16, 16), 256, 0, stream>>>(xb, w1, enc_fc1_b + (size_t)n * 1024,
                                                    nullptr, hb, 1024, 1024);
    const u16* w2;
    if (tier == 2) w2 = efc2T + (size_t)n * 1048576;
    else {
      transpose_w<<<dim3(32, 32, 1), tb, 0, stream>>>(enc_fc2_w + (size_t)n * 1048576, fcT_d, 1024, 1024);
      w2 = fcT_d;
    }
    gemm_fc<false><<<dim3(16, 16), 256, 0, stream>>>(hb, w2, enc_fc2_b + (size_t)n * 1024,
                                                     x32, d32, 1024, 1024);
    ln_k<<<1024, 256, 0, stream>>>(d32, enc_ln_g + (size_t)(n * 2 + 1) * 1024,
                                   enc_ln_bb + (size_t)(n * 2 + 1) * 1024, x32, xb);
  }
  // decoder (enc_out lives in xb)
  for (int n = 0; n < 4; n++) {
    const u16* wq;
    if (tier == 2) wq = dsqkvT + (size_t)n * 3145728;
    else {
      transpose_w<<<dim3(32, 2, 48), tb, 0, stream>>>(dec_self_qkv_w + (size_t)n * 48 * 65536, qkvT_d, 1024, 64);
      wq = qkvT_d;
    }
    gemm_qkv3<<<dim3(48, 16), 256, 0, stream>>>(yb, yb, wq, dec_self_qkv_b + (size_t)n * 3072, Qb, Kb, Vtb);
    attn_k<true><<<dim3(8, 32), 256, 0, stream>>>(Qb, Kb, Vtb, y32, d32);
    ln_k<<<1024, 256, 0, stream>>>(d32, dec_ln_g + (size_t)(n * 3) * 1024,
                                   dec_ln_bb + (size_t)(n * 3) * 1024, y32, yb);
    if (tier == 2) wq = dcqkvT + (size_t)n * 3145728;
    else {
      transpose_w<<<dim3(32, 2, 48), tb, 0, stream>>>(dec_cross_qkv_w + (size_t)n * 48 * 65536, qkvT_d, 1024, 64);
      wq = qkvT_d;
    }
    gemm_qkv3<<<dim3(48, 16), 256, 0, stream>>>(yb, xb, wq, dec_cross_qkv_b + (size_t)n * 3072, Qb, Kb, Vtb);
    attn_k<false><<<dim3(8, 32), 256, 0, stream>>>(Qb, Kb, Vtb, y32, d32);
    ln_k<<<1024, 256, 0, stream>>>(d32, dec_ln_g + (size_t)(n * 3 + 1) * 1024,
                                   dec_ln_bb + (size_t)(n * 3 + 1) * 1024, y32, yb);
    const u16* w1;
    if (tier == 2) w1 = dfc1T + (size_t)n * 1048576;
    else {
      transpose_w<<<dim3(32, 32, 1), tb, 0, stream>>>(dec_fc1_w + (size_t)n * 1048576, fcT_d, 1024, 1024);
      w1 = fcT_d;
    }
    gemm_fc<true><<<dim3(16, 16), 256, 0, stream>>>(yb, w1, dec_fc1_b + (size_t)n * 1024,
                                                    nullptr, hb, 1024, 1024);
    const u16* w2;
    if (tier == 2) w2 = dfc2T + (size_t)n * 1048576;
    else {
      transpose_w<<<dim3(32, 32, 1), tb, 0, stream>>>(dec_fc2_w + (size_t)n * 1048576, fcT_d, 1024, 1024);
      w2 = fcT_d;
    }
    gemm_fc<false><<<dim3(16, 16), 256, 0, stream>>>(hb, w2, dec_fc2_b + (size_t)n * 1024,
                                                     y32, d32, 1024, 1024);
    ln_k<<<1024, 256, 0, stream>>>(d32, dec_ln_g + (size_t)(n * 3 + 2) * 1024,
                                   dec_ln_bb + (size_t)(n * 3 + 2) * 1024, y32, yb);
  }
  // final projection -> d_out (f32); reads only yb/outwT (in d_ws)
  if (tier >= 1)
    gemm_f256<<<dim3(512), 512, 0, stream>>>(yb, outwT, out_b, (float*)d_out, 32000, 1024);
  else
    gemm_bn<<<dim3(2048), 256, 0, stream>>>(yb, out_w, out_b, (float*)d_out, 32000, 1024);
}

// Round 16
// 941.811 us; speedup vs baseline: 1.0217x; 1.0123x over previous
//
#include <hip/hip_runtime.h>
#include <stdint.h>
#include <stddef.h>

typedef unsigned short u16;
typedef __attribute__((ext_vector_type(8))) short bf16x8;
typedef __attribute__((ext_vector_type(4))) float f32x4;

#define DEV __device__ __forceinline__

DEV float b2f(u16 u) { union { float f; uint32_t i; } v; v.i = ((uint32_t)u) << 16; return v.f; }
DEV u16 f2b(float f) {
  uint32_t x = __float_as_uint(f);
  x += 0x7fffu + ((x >> 16) & 1u);
  return (u16)(x >> 16);
}
DEV bf16x8 ld8f(const float* f) {
  float4 a = *(const float4*)f;
  float4 b = *(const float4*)(f + 4);
  bf16x8 r;
  ((u16*)&r)[0] = f2b(a.x); ((u16*)&r)[1] = f2b(a.y);
  ((u16*)&r)[2] = f2b(a.z); ((u16*)&r)[3] = f2b(a.w);
  ((u16*)&r)[4] = f2b(b.x); ((u16*)&r)[5] = f2b(b.y);
  ((u16*)&r)[6] = f2b(b.z); ((u16*)&r)[7] = f2b(b.w);
  return r;
}
DEV void gload16(const u16* g, u16* l) {
  __builtin_amdgcn_global_load_lds((const __attribute__((address_space(1))) void*)g,
                                   (__attribute__((address_space(3))) void*)l, 16, 0, 0);
}
DEV f32x4 mfma16(bf16x8 a, bf16x8 b, f32x4 c) {
  return __builtin_amdgcn_mfma_f32_16x16x32_bf16(a, b, c, 0, 0, 0);
}

// ---------- transpose f32 [K][N] -> bf16 [N][K], batched over z (tier0/1 path) ----------
__global__ __launch_bounds__(256) void transpose_w(const float* __restrict__ src,
                                                   u16* __restrict__ dst, int K, int N) {
  __shared__ u16 t[32][33];
  int tx = threadIdx.x, ty = threadIdx.y;
  int k0 = blockIdx.x * 32, n0 = blockIdx.y * 32;
  size_t base = (size_t)blockIdx.z * K * N;
#pragma unroll
  for (int i = 0; i < 4; i++) {
    int k = ty + 8 * i;
    t[k][tx] = f2b(src[base + (size_t)(k0 + k) * N + n0 + tx]);
  }
  __syncthreads();
#pragma unroll
  for (int i = 0; i < 4; i++) {
    int n = ty + 8 * i;
    dst[base + (size_t)(n0 + n) * K + k0 + tx] = t[tx][n];
  }
}

// ---------- merged QKV weight transpose: 3 tensors x 192 [1024][64] -> [N][K] bf16 ----------
__global__ __launch_bounds__(256) void transpose_qkvT(const float* __restrict__ s0,
                                                      const float* __restrict__ s1,
                                                      const float* __restrict__ s2,
                                                      u16* __restrict__ dst) {
  int z = blockIdx.z;
  const float* src = (z < 192) ? s0 : (z < 384) ? s1 : s2;
  int zi = (z < 192) ? z : (z < 384) ? z - 192 : z - 384;
  size_t sbase = (size_t)zi * 65536;
  size_t dbase = (size_t)z * 65536;
  __shared__ u16 t[32][33];
  int tx = threadIdx.x, ty = threadIdx.y;
  int k0 = blockIdx.x * 32, n0 = blockIdx.y * 32;
#pragma unroll
  for (int i = 0; i < 4; i++) {
    int k = ty + 8 * i;
    t[k][tx] = f2b(src[sbase + (size_t)(k0 + k) * 64 + n0 + tx]);
  }
  __syncthreads();
#pragma unroll
  for (int i = 0; i < 4; i++) {
    int n = ty + 8 * i;
    dst[dbase + (size_t)(n0 + n) * 1024 + k0 + tx] = t[tx][n];
  }
}

// ---------- merged FC weight transpose: 4 tensors x 4 layers [1024][1024] ----------
__global__ __launch_bounds__(256) void transpose_fcT(const float* __restrict__ s0,
                                                     const float* __restrict__ s1,
                                                     const float* __restrict__ s2,
                                                     const float* __restrict__ s3,
                                                     u16* __restrict__ dst) {
  int z = blockIdx.z;
  const float* src = (z < 4) ? s0 : (z < 8) ? s1 : (z < 12) ? s2 : s3;
  size_t sbase = (size_t)(z & 3) * 1048576;
  size_t dbase = (size_t)z * 1048576;
  __shared__ u16 t[32][33];
  int tx = threadIdx.x, ty = threadIdx.y;
  int k0 = blockIdx.x * 32, n0 = blockIdx.y * 32;
#pragma unroll
  for (int i = 0; i < 4; i++) {
    int k = ty + 8 * i;
    t[k][tx] = f2b(src[sbase + (size_t)(k0 + k) * 1024 + n0 + tx]);
  }
  __syncthreads();
#pragma unroll
  for (int i = 0; i < 4; i++) {
    int n = ty + 8 * i;
    dst[dbase + (size_t)(n0 + n) * 1024 + k0 + tx] = t[tx][n];
  }
}

// ---------- embedding gather + sinusoidal positional encoding ----------
__global__ __launch_bounds__(256) void embed_k(const int* __restrict__ tok, const float* __restrict__ emb,
                                               float* __restrict__ o32, u16* __restrict__ ob, int shift) {
  int row = blockIdx.x;
  int b = row >> 9, l = row & 511;
  int tk = tok[(size_t)(l + shift) * 2 + b];
  const float* e = emb + (size_t)tk * 1024;
  const float c0 = -9.210340371976184f / 1024.f;
#pragma unroll
  for (int i = 0; i < 4; i++) {
    int d = threadIdx.x + i * 256;
    int j2 = d & ~1;
    float ang = (float)l * expf(c0 * (float)j2);
    float pe = (d & 1) ? cosf(ang) : sinf(ang);
    float rv = e[d] + pe;
    o32[(size_t)row * 1024 + d] = rv;
    ob[(size_t)row * 1024 + d] = f2b(rv);
  }
}

// ---------- LayerNorm (input d already includes residual), fp32 in, fp32+bf16 out ----------
__global__ __launch_bounds__(256) void ln_k(const float* d,
                                            const float* __restrict__ g, const float* __restrict__ bb,
                                            float* o32, u16* __restrict__ ob) {
  int row = blockIdx.x;
  int tid = threadIdx.x;
  const float4 dv = ((const float4*)(d + (size_t)row * 1024))[tid];
  float v[4] = {dv.x, dv.y, dv.z, dv.w};
  float s = 0.f, s2 = 0.f;
#pragma unroll
  for (int i = 0; i < 4; i++) { s += v[i]; s2 += v[i] * v[i]; }
#pragma unroll
  for (int off = 1; off < 64; off <<= 1) {
    s += __shfl_xor(s, off);
    s2 += __shfl_xor(s2, off);
  }
  __shared__ float red[8];
  int wid = tid >> 6;
  if ((tid & 63) == 0) { red[wid * 2] = s; red[wid * 2 + 1] = s2; }
  __syncthreads();
  s = red[0] + red[2] + red[4] + red[6];
  s2 = red[1] + red[3] + red[5] + red[7];
  float mu = s * (1.f / 1024.f);
  float var = s2 * (1.f / 1024.f) - mu * mu;
  float inv = rsqrtf(var + 1e-5f);
  const float4 gv = ((const float4*)g)[tid];
  const float4 bv = ((const float4*)bb)[tid];
  float4 ov;
  ov.x = (v[0] - mu) * inv * gv.x + bv.x;
  ov.y = (v[1] - mu) * inv * gv.y + bv.y;
  ov.z = (v[2] - mu) * inv * gv.z + bv.z;
  ov.w = (v[3] - mu) * inv * gv.w + bv.w;
  ((float4*)(o32 + (size_t)row * 1024))[tid] = ov;
  uint2 p;
  p.x = (uint32_t)f2b(ov.x) | ((uint32_t)f2b(ov.y) << 16);
  p.y = (uint32_t)f2b(ov.z) | ((uint32_t)f2b(ov.w) << 16);
  ((uint2*)(ob + (size_t)row * 1024))[tid] = p;
}

// ---------- FFN GEMM: 64x64 tile, BK=64, depth-2 counted-vmcnt pipeline ----------
template <bool RELU>
__global__ __launch_bounds__(256) void gemm_fc(const u16* __restrict__ A, const u16* __restrict__ BT,
                                               const float* __restrict__ bias,
                                               const float* __restrict__ resid, void* __restrict__ out,
                                               int N, int K) {
  __shared__ __align__(16) u16 lA[2][2][64 * 32];
  __shared__ __align__(16) u16 lB[2][2][64 * 32];
  int bx = blockIdx.x, by = blockIdx.y;
  int tid = threadIdx.x, lane = tid & 63, wid = tid >> 6;
  int l15 = lane & 15, lg = lane >> 4;
  int bm = by * 64, bn = bx * 64;
  int wr = (wid >> 1) * 32, wc = (wid & 1) * 32;
  f32x4 acc[2][2] = {};
  int r_s = tid >> 2, c_s = tid & 3;
  auto stage = [&](int pp, int kt) {
#pragma unroll
    for (int s = 0; s < 2; s++) {
      gload16(A + (size_t)(bm + r_s) * K + kt + s * 32 + c_s * 8, &lA[pp][s][(size_t)(wid * 64) * 8]);
      gload16(BT + (size_t)(bn + r_s) * K + kt + s * 32 + c_s * 8, &lB[pp][s][(size_t)(wid * 64) * 8]);
    }
  };
  int nt = K >> 6;
  stage(0, 0);
  int pp = 0;
  for (int t = 0; t < nt; t++) {
    if (t + 1 < nt) {
      stage(pp ^ 1, (t + 1) * 64);
      asm volatile("s_waitcnt vmcnt(4)" ::: "memory");
    } else {
      asm volatile("s_waitcnt vmcnt(0)" ::: "memory");
    }
    __builtin_amdgcn_s_barrier();
#pragma unroll
    for (int s = 0; s < 2; s++) {
      bf16x8 af[2], bf_[2];
#pragma unroll
      for (int m = 0; m < 2; m++) af[m] = *(const bf16x8*)&lA[pp][s][(wr + m * 16 + l15) * 32 + lg * 8];
#pragma unroll
      for (int n = 0; n < 2; n++) bf_[n] = *(const bf16x8*)&lB[pp][s][(wc + n * 16 + l15) * 32 + lg * 8];
#pragma unroll
      for (int m = 0; m < 2; m++)
#pragma unroll
        for (int n = 0; n < 2; n++) acc[m][n] = mfma16(af[m], bf_[n], acc[m][n]);
    }
    __builtin_amdgcn_s_barrier();
    pp ^= 1;
  }
#pragma unroll
  for (int n = 0; n < 2; n++) {
    int col = bn + wc + n * 16 + l15;
    float bv = bias[col];
#pragma unroll
    for (int m = 0; m < 2; m++) {
#pragma unroll
      for (int r = 0; r < 4; r++) {
        int row = bm + wr + m * 16 + lg * 4 + r;
        float v = acc[m][n][r] + bv;
        if (RELU) ((u16*)out)[(size_t)row * N + col] = f2b(fmaxf(v, 0.f));
        else ((float*)out)[(size_t)row * N + col] = v + resid[(size_t)row * N + col];
      }
    }
  }
}

// ---------- fused QKV projection, 64x64 tiles, BK=64, depth-2 pipeline ----------
__global__ __launch_bounds__(256) void gemm_qkv3(const u16* __restrict__ Aq, const u16* __restrict__ Akv,
                                                 const u16* __restrict__ WT, const float* __restrict__ bias,
                                                 u16* __restrict__ Qo, u16* __restrict__ Ko,
                                                 u16* __restrict__ Vto) {
  __shared__ __align__(16) u16 lA[2][2][64 * 32];
  __shared__ __align__(16) u16 lB[2][2][64 * 32];
  int bx = blockIdx.x, by = blockIdx.y;
  int t_ = bx >> 4;
  const u16* A = (t_ == 0) ? Aq : Akv;
  int tid = threadIdx.x, lane = tid & 63, wid = tid >> 6;
  int l15 = lane & 15, lg = lane >> 4;
  int bm = by * 64, bn = bx * 64;
  int wr = (wid >> 1) * 32, wc = (wid & 1) * 32;
  f32x4 acc[2][2] = {};
  int r_s = tid >> 2, c_s = tid & 3;
  auto stage = [&](int pp, int kt) {
#pragma unroll
    for (int s = 0; s < 2; s++) {
      gload16(A + (size_t)(bm + r_s) * 1024 + kt + s * 32 + c_s * 8, &lA[pp][s][(size_t)(wid * 64) * 8]);
      gload16(WT + (size_t)(bn + r_s) * 1024 + kt + s * 32 + c_s * 8, &lB[pp][s][(size_t)(wid * 64) * 8]);
    }
  };
  stage(0, 0);
  int pp = 0;
  for (int t = 0; t < 16; t++) {
    if (t + 1 < 16) {
      stage(pp ^ 1, (t + 1) * 64);
      asm volatile("s_waitcnt vmcnt(4)" ::: "memory");
    } else {
      asm volatile("s_waitcnt vmcnt(0)" ::: "memory");
    }
    __builtin_amdgcn_s_barrier();
#pragma unroll
    for (int s = 0; s < 2; s++) {
      bf16x8 af[2], bf_[2];
#pragma unroll
      for (int m = 0; m < 2; m++) af[m] = *(const bf16x8*)&lA[pp][s][(wr + m * 16 + l15) * 32 + lg * 8];
#pragma unroll
      for (int n = 0; n < 2; n++) bf_[n] = *(const bf16x8*)&lB[pp][s][(wc + n * 16 + l15) * 32 + lg * 8];
#pragma unroll
      for (int m = 0; m < 2; m++)
#pragma unroll
        for (int n = 0; n < 2; n++) acc[m][n] = mfma16(af[m], bf_[n], acc[m][n]);
    }
    __builtin_amdgcn_s_barrier();
    pp ^= 1;
  }
#pragma unroll
  for (int n = 0; n < 2; n++) {
    int col = bn + wc + n * 16 + l15;
    int h = (col >> 6) & 15, e = col & 63;
    float bv = bias[col];
#pragma unroll
    for (int m = 0; m < 2; m++) {
#pragma unroll
      for (int r = 0; r < 4; r++) {
        int row = bm + wr + m * 16 + lg * 4 + r;
        int b = row >> 9, l = row & 511;
        u16 vbv = f2b(acc[m][n][r] + bv);
        size_t bhead = (size_t)b * 16 + h;
        if (t_ == 0) Qo[(bhead * 512 + l) * 64 + e] = vbv;
        else if (t_ == 1) Ko[(bhead * 512 + l) * 64 + e] = vbv;
        else Vto[(bhead * 64 + e) * 512 + l] = vbv;
      }
    }
  }
}

// ---------- final projection: 256x256 tile, 8 waves, BK=64, depth-2, XOR bank swizzle ----------
// LDS [256][64] u16 rows (128 B stride) are a 16-way conflict unswizzled; store global
// chunk c^(row&7) at linear chunk c (rule #21: linear LDS dest + pre-swizzled SOURCE),
// read chunk (kk*4+lg)^(row&7) -> all 32 banks, 2 lanes each (free).
__global__ __launch_bounds__(512) void gemm_f256(const u16* __restrict__ A, const u16* __restrict__ BT,
                                                 const float* __restrict__ bias, float* __restrict__ out,
                                                 int N, int K) {
  __shared__ __align__(16) u16 lA[2][256 * 64];
  __shared__ __align__(16) u16 lB[2][256 * 64];
  int b = blockIdx.x;
  int p = (b & 7) + 8 * (b >> 5);
  if (p >= N / 256) return;
  int brow = (b >> 3) & 3;
  int tid = threadIdx.x, lane = tid & 63, wid = tid >> 6;
  int l15 = lane & 15, lg = lane >> 4;
  int bm = brow * 256, bn = p * 256;
  int wrow = (wid >> 2) * 128, wcol = (wid & 3) * 64;  // 8 waves = 2M x 4N; per wave 128x64
  f32x4 acc[8][4] = {};
  auto stage = [&](int pp, int kt) {
#pragma unroll
    for (int i = 0; i < 4; i++) {  // A: 256 rows x 8 chunks of 16B
      int c = i * 512 + tid;
      int row = c >> 3, kc = (c & 7) ^ (row & 7);  // pre-swizzled source chunk
      gload16(A + (size_t)(bm + row) * K + kt + kc * 8, &lA[pp][(size_t)c * 8]);
    }
#pragma unroll
    for (int i = 0; i < 4; i++) {
      int c = i * 512 + tid;
      int row = c >> 3, kc = (c & 7) ^ (row & 7);
      gload16(BT + (size_t)(bn + row) * K + kt + kc * 8, &lB[pp][(size_t)c * 8]);
    }
  };
  int nt = K >> 6;  // 16
  stage(0, 0);
  int pp = 0;
  for (int t = 0; t < nt; t++) {
    if (t + 1 < nt) {
      stage(pp ^ 1, (t + 1) * 64);
      asm volatile("s_waitcnt vmcnt(8)" ::: "memory");  // stage t landed; t+1's 8 in flight
    } else {
      asm volatile("s_waitcnt vmcnt(0)" ::: "memory");
    }
    __builtin_amdgcn_s_barrier();
#pragma unroll
    for (int kk = 0; kk < 2; kk++) {
      bf16x8 af[8], bf_[4];
#pragma unroll
      for (int m = 0; m < 8; m++) {
        int row = wrow + m * 16 + l15;
        int q = (kk * 4 + lg) ^ (row & 7);  // same-involution read chunk
        af[m] = *(const bf16x8*)&lA[pp][row * 64 + q * 8];
      }
#pragma unroll
      for (int n = 0; n < 4; n++) {
        int row = wcol + n * 16 + l15;
        int q = (kk * 4 + lg) ^ (row & 7);
        bf_[n] = *(const bf16x8*)&lB[pp][row * 64 + q * 8];
      }
#pragma unroll
      for (int m = 0; m < 8; m++)
#pragma unroll
        for (int n = 0; n < 4; n++) acc[m][n] = mfma16(af[m], bf_[n], acc[m][n]);
    }
    __builtin_amdgcn_s_barrier();
    pp ^= 1;
  }
#pragma unroll
  for (int n = 0; n < 4; n++) {
    int col = bn + wcol + n * 16 + l15;
    float bv = bias[col];
#pragma unroll
    for (int m = 0; m < 8; m++) {
#pragma unroll
      for (int r = 0; r < 4; r++) {
        int row = bm + wrow + m * 16 + lg * 4 + r;
        out[(size_t)row * N + col] = acc[m][n][r] + bv;
      }
    }
  }
}

// ---------- fallback final projection (tier0): A bf16; B f32 [K][N]; out f32 ----------
__global__ __launch_bounds__(256) void gemm_bn(const u16* __restrict__ A, const float* __restrict__ B,
                                               const float* __restrict__ bias, float* __restrict__ out,
                                               int N, int K) {
  __shared__ __align__(16) u16 lA[128 * 32];
  __shared__ __align__(16) u16 lBn[32 * 128];
  int b = blockIdx.x;
  int p = (b & 7) + 8 * (b >> 6);
  if (p >= N / 128) return;
  int by = (b >> 3) & 7;
  int tid = threadIdx.x, lane = tid & 63;
  int wid = tid >> 6;
  int l15 = lane & 15, lg = lane >> 4;
  int bm = by * 128, bn = p * 128;
  int wr = (wid >> 1) * 64, wc = (wid & 1) * 64;
  f32x4 acc[4][4] = {};
  int r_s = tid >> 2, c_s = tid & 3;
  int br = tid >> 4, bc = tid & 15;
  for (int kt = 0; kt < K; kt += 32) {
    bf16x8 va[2], vb[2];
#pragma unroll
    for (int it = 0; it < 2; it++) {
      va[it] = *(const bf16x8*)&A[(size_t)(bm + it * 64 + r_s) * K + kt + c_s * 8];
      vb[it] = ld8f(B + (size_t)(kt + it * 16 + br) * N + bn + bc * 8);
    }
    __syncthreads();
#pragma unroll
    for (int it = 0; it < 2; it++) {
      *(bf16x8*)&lA[(size_t)(it * 256 + tid) * 8] = va[it];
      *(bf16x8*)&lBn[(size_t)(it * 256 + tid) * 8] = vb[it];
    }
    __syncthreads();
    bf16x8 af[4], bfr[4];
#pragma unroll
    for (int m = 0; m < 4; m++) af[m] = *(const bf16x8*)&lA[(wr + m * 16 + l15) * 32 + lg * 8];
#pragma unroll
    for (int n = 0; n < 4; n++) {
#pragma unroll
      for (int j = 0; j < 8; j++)
        ((short*)&bfr[n])[j] = (short)lBn[(lg * 8 + j) * 128 + wc + n * 16 + l15];
    }
#pragma unroll
    for (int m = 0; m < 4; m++)
#pragma unroll
      for (int n = 0; n < 4; n++) acc[m][n] = mfma16(af[m], bfr[n], acc[m][n]);
  }
#pragma unroll
  for (int n = 0; n < 4; n++) {
    int col = bn + wc + n * 16 + l15;
    float bv = bias[col];
#pragma unroll
    for (int m = 0; m < 4; m++) {
#pragma unroll
      for (int r = 0; r < 4; r++) {
        int row = bm + wr + m * 16 + lg * 4 + r;
        out[(size_t)row * N + col] = acc[m][n][r] + bv;
      }
    }
  }
}

// ---------- fused flash attention, no-max softmax, K-tile register prefetch ----------
template <bool CAUSAL>
__global__ __launch_bounds__(256) void attn_k(const u16* __restrict__ Qb, const u16* __restrict__ Kb,
                                              const u16* __restrict__ Vtb, const float* __restrict__ R,
                                              float* __restrict__ Ob) {
  int bh = blockIdx.y;
  int tid = threadIdx.x, lane = tid & 63, w = tid >> 6;
  int l15 = lane & 15, lg = lane >> 4;
  int q0 = blockIdx.x * 64 + w * 16;
  const u16* Qh = Qb + (size_t)bh * 512 * 64;
  const u16* Kh = Kb + (size_t)bh * 512 * 64;
  const u16* Vh = Vtb + (size_t)bh * 64 * 512;
  __shared__ __align__(16) u16 P[4][16 * 40];
  u16* Pw = &P[w][0];
  bf16x8 qa0 = *(const bf16x8*)&Qh[(size_t)(q0 + l15) * 64 + lg * 8];
  bf16x8 qa1 = *(const bf16x8*)&Qh[(size_t)(q0 + l15) * 64 + 32 + lg * 8];
  f32x4 acc[4];
#pragma unroll
  for (int c = 0; c < 4; c++) acc[c] = (f32x4){0.f, 0.f, 0.f, 0.f};
  float ls[4] = {0.f, 0.f, 0.f, 0.f};
  int ktend = CAUSAL ? ((q0 + 15) >> 5) : 15;
  bf16x8 kn00 = *(const bf16x8*)&Kh[(size_t)(l15) * 64 + lg * 8];
  bf16x8 kn01 = *(const bf16x8*)&Kh[(size_t)(l15) * 64 + 32 + lg * 8];
  bf16x8 kn10 = *(const bf16x8*)&Kh[(size_t)(16 + l15) * 64 + lg * 8];
  bf16x8 kn11 = *(const bf16x8*)&Kh[(size_t)(16 + l15) * 64 + 32 + lg * 8];
  for (int kt = 0; kt <= ktend; kt++) {
    int kv = kt * 32;
    bf16x8 c00 = kn00, c01 = kn01, c10 = kn10, c11 = kn11;
    if (kt < ktend) {
      int kv2 = kv + 32;
      kn00 = *(const bf16x8*)&Kh[(size_t)(kv2 + l15) * 64 + lg * 8];
      kn01 = *(const bf16x8*)&Kh[(size_t)(kv2 + l15) * 64 + 32 + lg * 8];
      kn10 = *(const bf16x8*)&Kh[(size_t)(kv2 + 16 + l15) * 64 + lg * 8];
      kn11 = *(const bf16x8*)&Kh[(size_t)(kv2 + 16 + l15) * 64 + 32 + lg * 8];
    }
    f32x4 z = (f32x4){0.f, 0.f, 0.f, 0.f};
    f32x4 s0 = mfma16(qa0, c00, z);
    s0 = mfma16(qa1, c01, s0);
    f32x4 s1 = mfma16(qa0, c10, z);
    s1 = mfma16(qa1, c11, s1);
#pragma unroll
    for (int r = 0; r < 4; r++) {
      float a0 = s0[r] * 0.125f, a1 = s1[r] * 0.125f;
      if (CAUSAL) {
        int rowg = q0 + lg * 4 + r;
        if (kv + l15 > rowg) a0 = -1e30f;
        if (kv + 16 + l15 > rowg) a1 = -1e30f;
      }
      float p0 = __expf(a0), p1 = __expf(a1);
      ls[r] += p0 + p1;
      int prow = lg * 4 + r;
      Pw[prow * 40 + l15] = f2b(p0);
      Pw[prow * 40 + 16 + l15] = f2b(p1);
    }
    bf16x8 pa = *(const bf16x8*)&Pw[l15 * 40 + lg * 8];
#pragma unroll
    for (int c = 0; c < 4; c++) {
      bf16x8 vb = *(const bf16x8*)&Vh[(size_t)(c * 16 + l15) * 512 + kv + lg * 8];
      acc[c] = mfma16(pa, vb, acc[c]);
    }
  }
#pragma unroll
  for (int r = 0; r < 4; r++) {
#pragma unroll
    for (int off = 1; off < 16; off <<= 1) ls[r] += __shfl_xor(ls[r], off);
  }
  int b = bh >> 4, h = bh & 15;
#pragma unroll
  for (int r = 0; r < 4; r++) {
    float inv = 1.f / ls[r];
    int rowg = q0 + lg * 4 + r;
    size_t off0 = (size_t)(b * 512 + rowg) * 1024 + h * 64;
#pragma unroll
    for (int c = 0; c < 4; c++)
      Ob[off0 + c * 16 + l15] = R[off0 + c * 16 + l15] + acc[c][r] * inv;
  }
}

// ------------------------------- launch -------------------------------
extern "C" void kernel_launch(void* const* d_in, const int* in_sizes, int n_in,
                              void* d_out, int out_size, void* d_ws, size_t ws_size,
                              hipStream_t stream) {
  const int* fr = (const int*)d_in[0];
  const int* en = (const int*)d_in[1];
  const float* emb_fr = (const float*)d_in[2];
  const float* emb_en = (const float*)d_in[3];
  const float* enc_qkv_w = (const float*)d_in[4];
  const float* enc_qkv_b = (const float*)d_in[5];
  const float* enc_fc1_w = (const float*)d_in[6];
  const float* enc_fc1_b = (const float*)d_in[7];
  const float* enc_fc2_w = (const float*)d_in[8];
  const float* enc_fc2_b = (const float*)d_in[9];
  const float* enc_ln_g = (const float*)d_in[10];
  const float* enc_ln_bb = (const float*)d_in[11];
  const float* dec_self_qkv_w = (const float*)d_in[12];
  const float* dec_self_qkv_b = (const float*)d_in[13];
  const float* dec_cross_qkv_w = (const float*)d_in[14];
  const float* dec_cross_qkv_b = (const float*)d_in[15];
  const float* dec_fc1_w = (const float*)d_in[16];
  const float* dec_fc1_b = (const float*)d_in[17];
  const float* dec_fc2_w = (const float*)d_in[18];
  const float* dec_fc2_b = (const float*)d_in[19];
  const float* dec_ln_g = (const float*)d_in[20];
  const float* dec_ln_bb = (const float*)d_in[21];
  const float* out_w = (const float*)d_in[22];
  const float* out_b = (const float*)d_in[23];

  // scratch inside d_out (final GEMM reads only yb/outwT in d_ws, overwrites d_out)
  char* o8 = (char*)d_out;
  u16* qkvT_d = (u16*)o8;
  u16* fcT_d = (u16*)(o8 + 6291456);
  float* x32 = (float*)(o8 + 8388608);
  float* y32 = (float*)(o8 + 12582912);
  float* d32 = (float*)(o8 + 16777216);
  u16* xb = (u16*)(o8 + 20971520);
  u16* hb = (u16*)(o8 + 23068672);
  u16* Qb = (u16*)(o8 + 25165824);
  u16* Kb = (u16*)(o8 + 27262976);
  u16* Vtb = (u16*)(o8 + 29360128);

  // ws tiers
  char* w8 = (char*)d_ws;
  u16* yb = (u16*)w8;
  u16* outwT = (u16*)(w8 + 2097152);
  u16* eqkvT = (u16*)(w8 + 67633152);
  u16* dsqkvT = (u16*)(w8 + 92798976);
  u16* dcqkvT = (u16*)(w8 + 117964800);
  u16* efc1T = (u16*)(w8 + 143130624);
  u16* efc2T = (u16*)(w8 + 151519232);
  u16* dfc1T = (u16*)(w8 + 159907840);
  u16* dfc2T = (u16*)(w8 + 168296448);
  int tier = (ws_size >= 176685056u) ? 2 : (ws_size >= 67633152u) ? 1 : 0;

  dim3 tb(32, 8);
  if (tier >= 1)
    transpose_w<<<dim3(32, 1000, 1), tb, 0, stream>>>(out_w, outwT, 1024, 32000);
  if (tier == 2) {
    transpose_qkvT<<<dim3(32, 2, 576), tb, 0, stream>>>(enc_qkv_w, dec_self_qkv_w, dec_cross_qkv_w, eqkvT);
    transpose_fcT<<<dim3(32, 32, 16), tb, 0, stream>>>(enc_fc1_w, enc_fc2_w, dec_fc1_w, dec_fc2_w, efc1T);
  }

  embed_k<<<1024, 256, 0, stream>>>(fr, emb_fr, x32, xb, 1);
  embed_k<<<1024, 256, 0, stream>>>(en, emb_en, y32, yb, 0);

  // encoder
  for (int n = 0; n < 4; n++) {
    const u16* wqkv;
    if (tier == 2) wqkv = eqkvT + (size_t)n * 3145728;
    else {
      transpose_w<<<dim3(32, 2, 48), tb, 0, stream>>>(enc_qkv_w + (size_t)n * 48 * 65536, qkvT_d, 1024, 64);
      wqkv = qkvT_d;
    }
    gemm_qkv3<<<dim3(48, 16), 256, 0, stream>>>(xb, xb, wqkv, enc_qkv_b + (size_t)n * 3072, Qb, Kb, Vtb);
    attn_k<false><<<dim3(8, 32), 256, 0, stream>>>(Qb, Kb, Vtb, x32, d32);
    ln_k<<<1024, 256, 0, stream>>>(d32, enc_ln_g + (size_t)(n * 2) * 1024,
                                   enc_ln_bb + (size_t)(n * 2) * 1024, x32, xb);
    const u16* w1;
    if (tier == 2) w1 = efc1T + (size_t)n * 1048576;
    else {
      transpose_w<<<dim3(32, 32, 1), tb, 0, stream>>>(enc_fc1_w + (size_t)n * 1048576, fcT_d, 1024, 1024);
      w1 = fcT_d;
    }
    gemm_fc<true><<<dim3(16, 16), 256, 0, stream>>>(xb, w1, enc_fc1_b + (size_t)n * 1024,
                                                    nullptr, hb, 1024, 1024);
    const u16* w2;
    if (tier == 2) w2 = efc2T + (size_t)n * 1048576;
    else {
      transpose_w<<<dim3(32, 32, 1), tb, 0, stream>>>(enc_fc2_w + (size_t)n * 1048576, fcT_d, 1024, 1024);
      w2 = fcT_d;
    }
    gemm_fc<false><<<dim3(16, 16), 256, 0, stream>>>(hb, w2, enc_fc2_b + (size_t)n * 1024,
                                                     x32, d32, 1024, 1024);
    ln_k<<<1024, 256, 0, stream>>>(d32, enc_ln_g + (size_t)(n * 2 + 1) * 1024,
                                   enc_ln_bb + (size_t)(n * 2 + 1) * 1024, x32, xb);
  }
  // decoder (enc_out lives in xb)
  for (int n = 0; n < 4; n++) {
    const u16* wq;
    if (tier == 2) wq = dsqkvT + (size_t)n * 3145728;
    else {
      transpose_w<<<dim3(32, 2, 48), tb, 0, stream>>>(dec_self_qkv_w + (size_t)n * 48 * 65536, qkvT_d, 1024, 64);
      wq = qkvT_d;
    }
    gemm_qkv3<<<dim3(48, 16), 256, 0, stream>>>(yb, yb, wq, dec_self_qkv_b + (size_t)n * 3072, Qb, Kb, Vtb);
    attn_k<true><<<dim3(8, 32), 256, 0, stream>>>(Qb, Kb, Vtb, y32, d32);
    ln_k<<<1024, 256, 0, stream>>>(d32, dec_ln_g + (size_t)(n * 3) * 1024,
                                   dec_ln_bb + (size_t)(n * 3) * 1024, y32, yb);
    if (tier == 2) wq = dcqkvT + (size_t)n * 3145728;
    else {
      transpose_w<<<dim3(32, 2, 48), tb, 0, stream>>>(dec_cross_qkv_w + (size_t)n * 48 * 65536, qkvT_d, 1024, 64);
      wq = qkvT_d;
    }
    gemm_qkv3<<<dim3(48, 16), 256, 0, stream>>>(yb, xb, wq, dec_cross_qkv_b + (size_t)n * 3072, Qb, Kb, Vtb);
    attn_k<false><<<dim3(8, 32), 256, 0, stream>>>(Qb, Kb, Vtb, y32, d32);
    ln_k<<<1024, 256, 0, stream>>>(d32, dec_ln_g + (size_t)(n * 3 + 1) * 1024,
                                   dec_ln_bb + (size_t)(n * 3 + 1) * 1024, y32, yb);
    const u16* w1;
    if (tier == 2) w1 = dfc1T + (size_t)n * 1048576;
    else {
      transpose_w<<<dim3(32, 32, 1), tb, 0, stream>>>(dec_fc1_w + (size_t)n * 1048576, fcT_d, 1024, 1024);
      w1 = fcT_d;
    }
    gemm_fc<true><<<dim3(16, 16), 256, 0, stream>>>(yb, w1, dec_fc1_b + (size_t)n * 1024,
                                                    nullptr, hb, 1024, 1024);
    const u16* w2;
    if (tier == 2) w2 = dfc2T + (size_t)n * 1048576;
    else {
      transpose_w<<<dim3(32, 32, 1), tb, 0, stream>>>(dec_fc2_w + (size_t)n * 1048576, fcT_d, 1024, 1024);
      w2 = fcT_d;
    }
    gemm_fc<false><<<dim3(16, 16), 256, 0, stream>>>(hb, w2, dec_fc2_b + (size_t)n * 1024,
                                                     y32, d32, 1024, 1024);
    ln_k<<<1024, 256, 0, stream>>>(d32, dec_ln_g + (size_t)(n * 3 + 2) * 1024,
                                   dec_ln_bb + (size_t)(n * 3 + 2) * 1024, y32, yb);
  }
  // final projection -> d_out (f32); reads only yb/outwT (in d_ws)
  if (tier >= 1)
    gemm_f256<<<dim3(512), 512, 0, stream>>>(yb, outwT, out_b, (float*)d_out, 32000, 1024);
  else
    gemm_bn<<<dim3(2048), 256, 0, stream>>>(yb, out_w, out_b, (float*)d_out, 32000, 1024);
}